// Round 7
// baseline (1080.035 us; speedup 1.0000x reference)
//
#include <hip/hip_runtime.h>
#include <math.h>

#define DIM   64
#define MDIM  32
#define NLAY  16
#define PAD   1
#define NB    2
#define LL    96
#define NN    23
#define NNODE (NB*LL*NN)   /* 4416 */
#define EIN   129
#define EH    258          /* EIN*2 */
#define KP    272          /* EH padded to 17*16 */
#define NK0   17
#define NH    128          /* DIM*2 */
#define BPITCH 276         /* bS pitch shorts */
#define APITCH 276         /* aS pitch floats (16B rows) */
#define NOUT  516          /* 2*EH outs of the a/b GEMM */
#define NTILE 17           /* ceil(544/32) N-tiles for pre GEMM */
#define XP    104
#define HP    136
#define OP    560

typedef __attribute__((ext_vector_type(8)))  short        bf16x8;
typedef __attribute__((ext_vector_type(16))) float        f32x16;
typedef __attribute__((ext_vector_type(4)))  unsigned int uint4v;
typedef __attribute__((ext_vector_type(2)))  float        f32x2;
typedef __attribute__((ext_vector_type(4)))  float        f32x4;

__device__ __forceinline__ f32x2 mk2(float a, float b) { f32x2 r; r.x = a; r.y = b; return r; }

__device__ __forceinline__ float silu_f(float x) {
    float e = __expf(-x);
    return x * __builtin_amdgcn_rcpf(1.0f + e);
}
__device__ __forceinline__ f32x2 silu2(f32x2 x) {
    f32x2 t = x * (-1.44269504f);
    f32x2 e;
    e.x = __builtin_amdgcn_exp2f(t.x);
    e.y = __builtin_amdgcn_exp2f(t.y);
    f32x2 den = e + 1.0f;
    f32x2 r;
    r.x = __builtin_amdgcn_rcpf(den.x);
    r.y = __builtin_amdgcn_rcpf(den.y);
    return x * r;
}
__device__ __forceinline__ unsigned short bf16_rn(float x) {
    unsigned u = __float_as_uint(x);
    u += 0x7FFF + ((u >> 16) & 1);
    return (unsigned short)(u >> 16);
}
__device__ __forceinline__ float bf16_up(unsigned short h) {
    return __uint_as_float(((unsigned)h) << 16);
}
__device__ __forceinline__ f32x2 ub2(unsigned bw) {
    return mk2(__uint_as_float(bw << 16), __uint_as_float(bw & 0xFFFF0000u));
}
__device__ __forceinline__ unsigned hpack(f32x2 a2, f32x2 w2, f32x2 b2, f32x2 d2) {
    f32x2 x2 = a2 + b2;
    x2 = __builtin_elementwise_fma(d2, w2, x2);
    f32x2 h2 = silu2(x2);
    return __builtin_amdgcn_perm(__float_as_uint(h2.y), __float_as_uint(h2.x), 0x07060302u);
}
__device__ __forceinline__ int fwd_map(int nf, int alongL) {
    if (alongL) {
        int b = nf / (LL * NN);
        int rem = nf % (LL * NN);
        int l = rem / NN, n = rem % NN;
        return (b * NN + n) * LL + l;
    }
    return nf;
}
__device__ __forceinline__ int inv_map(int gnode, int alongL) {
    if (alongL) {
        int g = gnode / LL, l = gnode % LL;
        int b = g / NN, n = g % NN;
        return (b * LL + l) * NN + n;
    }
    return gnode;
}

// ---------------------------------------------------------------------------
__global__ void k_embed(const int* __restrict__ tokens,
                        const float* __restrict__ tok_emb,
                        const float* __restrict__ pos_emb,
                        float* __restrict__ feats) {
    int idx = blockIdx.x * blockDim.x + threadIdx.x;
    if (idx < NNODE * DIM) {
        int node = idx / DIM, d = idx % DIM;
        int b = node / (LL * NN);
        int rem = node % (LL * NN);
        int n = rem % NN;
        int l = rem / NN;
        int t = tokens[b * LL + l];
        float f = tok_emb[t * DIM + d];
        if (t != PAD) f += pos_emb[(n + 2) * DIM + d];
        feats[idx] = f;
    }
}

// ---------------------------------------------------------------------------
__global__ void k_prep(const float* __restrict__ ew1, const float* __restrict__ ew2,
                       const float* __restrict__ cw1, const float* __restrict__ cb1,
                       const float* __restrict__ cw2,
                       const float* __restrict__ nw1, const float* __restrict__ nw2,
                       float* __restrict__ wdF, unsigned short* __restrict__ ew2P,
                       unsigned short* __restrict__ cw1P,
                       float* __restrict__ cbwP,
                       unsigned short* __restrict__ ew1P,
                       unsigned short* __restrict__ nw1P,
                       unsigned short* __restrict__ nw2P) {
    int idx = blockIdx.x * blockDim.x + threadIdx.x;
    if (idx < NLAY * KP) {
        int L = idx / KP, k = idx % KP;
        float v = (k < EH) ? ew1[(size_t)L * EIN * EH + 128 * EH + k] : 0.0f;
        wdF[idx] = bf16_up(bf16_rn(v));
    }
    if (idx < NLAY * NK0 * 512) {
        int L = idx / (NK0 * 512); int r = idx % (NK0 * 512);
        int k0 = r / 512; int r2 = r % 512;
        int lane = r2 >> 3, j = r2 & 7;
        int k = k0 * 16 + (lane >> 5) * 8 + j;
        int n = lane & 31;
        float v = (k < EH) ? ew2[((size_t)L * EH + k) * MDIM + n] : 0.0f;
        ew2P[idx] = bf16_rn(v);
    }
    if (idx < NLAY * 4096) {
        int L = idx / 4096; int r = idx % 4096;
        int mb = r / 1024; int r2 = r % 1024;
        int k0 = r2 / 512; int r3 = r2 % 512;
        int lane = r3 >> 3, j = r3 & 7;
        int k = k0 * 16 + (lane >> 5) * 8 + j;
        int o = mb * 32 + (lane & 31);
        cw1P[idx] = bf16_rn(cw1[((size_t)L * MDIM + k) * NH + o]);
    }
    if (idx < NLAY * 128) {
        int L = idx / 128; int r = idx % 128;
        int hlf = r / 64; int r2 = r % 64;
        int mb = r2 / 16, reg = r2 % 16;
        int o = mb * 32 + (reg & 3) + 8 * (reg >> 2) + 4 * hlf;
        cbwP[(size_t)L * 256 + r * 2 + 0] = cb1[L * NH + o];
        cbwP[(size_t)L * 256 + r * 2 + 1] = cw2[L * NH + o];
    }
    if (idx < NLAY * NTILE * 4 * 512) {
        int L = idx / (NTILE * 4 * 512); int r = idx % (NTILE * 4 * 512);
        int nt = r / 2048; int r2 = r % 2048;
        int ks = r2 / 512; int r3 = r2 % 512;
        int lane = r3 >> 3, j = r3 & 7;
        int d = ks * 16 + (lane >> 5) * 8 + j;
        int o = nt * 32 + (lane & 31);
        float v = 0.0f;
        if (o < EH)        v = ew1[(size_t)L * EIN * EH + d * EH + o];
        else if (o < NOUT) v = ew1[(size_t)L * EIN * EH + (DIM + d) * EH + (o - EH)];
        ew1P[idx] = bf16_rn(v);
    }
    if (idx < NLAY * 4 * 6 * 512) {
        int L = idx / 12288; int r = idx % 12288;
        int nt = r / 3072; int r2 = r % 3072;
        int ks = r2 / 512; int r3 = r2 % 512;
        int lane = r3 >> 3, j = r3 & 7;
        int k = ks * 16 + (lane >> 5) * 8 + j;
        int n = nt * 32 + (lane & 31);
        nw1P[idx] = bf16_rn(nw1[((size_t)L * (DIM + MDIM) + k) * NH + n]);
    }
    if (idx < NLAY * 2 * 8 * 512) {
        int L = idx / 8192; int r = idx % 8192;
        int nt = r / 4096; int r2 = r % 4096;
        int ks = r2 / 512; int r3 = r2 % 512;
        int lane = r3 >> 3, j = r3 & 7;
        int k = ks * 16 + (lane >> 5) * 8 + j;
        int n = nt * 32 + (lane & 31);
        nw2P[idx] = bf16_rn(nw2[((size_t)L * NH + k) * DIM + n]);
    }
}

// ---------------------------------------------------------------------------
// Fused node-MLP(L) + pre(L+1) (unchanged from R6).
// ---------------------------------------------------------------------------
__global__ __launch_bounds__(256)
void k_np(const float* __restrict__ fIn, const float* __restrict__ coSrc,
          const float* __restrict__ miL, const float* __restrict__ dL,
          const unsigned short* __restrict__ nw1PL, const float* __restrict__ nb1L,
          const unsigned short* __restrict__ nw2PL, const float* __restrict__ nb2L,
          const unsigned short* __restrict__ ew1PL, const float* __restrict__ eb1L,
          float* __restrict__ fOut, float* __restrict__ coDst,
          float* __restrict__ miNext, float* __restrict__ dNext,
          unsigned short* __restrict__ aH, unsigned short* __restrict__ bH,
          int aL0, int aL1, int doNode) {
    __shared__ unsigned short xS[32 * XP];
    __shared__ unsigned short hS[32 * HP];
    __shared__ unsigned short outS[32 * OP];
    __shared__ int gsrcS[32], gdstS[32];

    int n0  = blockIdx.x * 32;
    int tid = threadIdx.x;
    int wave = tid >> 6, lane = tid & 63, half = lane >> 5, e = lane & 31;

    if (tid < 32) {
        gsrcS[tid] = fwd_map(n0 + tid, aL0);
        gdstS[tid] = fwd_map(n0 + tid, aL1);
    }
    __syncthreads();

    for (int i = 0; i < 8; i++) {
        int x = tid + 256 * i;
        int node = x >> 6, d = x & 63;
        xS[node * XP + d] = bf16_rn(fIn[(n0 + node) * DIM + d]);
    }
    if (doNode) {
        for (int i = 0; i < 4; i++) {
            int x = tid + 256 * i;
            int node = x >> 5, d = x & 31;
            xS[node * XP + DIM + d] = bf16_rn(miL[(size_t)gsrcS[node] * MDIM + d]);
        }
    }
    for (int x = tid; x < 32 * 14; x += 256) {
        int node = x / 14, c = EH + x % 14;
        outS[node * OP + c] = 0;
    }
    if (tid < 96) {
        int node = tid / 3, c = tid % 3;
        int gs = gsrcS[node], gd = gdstS[node];
        float cv = coSrc[gs * 3 + c] + (doNode ? dL[gs * 3 + c] : 0.0f);
        coDst[gd * 3 + c] = cv;
        dNext[gd * 3 + c] = 0.0f;
    }
    for (int i = 0; i < 4; i++) {
        int x = tid + 256 * i;
        int node = x >> 5, d = x & 31;
        miNext[(size_t)gdstS[node] * MDIM + d] = 0.0f;
    }
    __syncthreads();

    if (doNode) {
        {
            int nt = wave;
            f32x16 acc;
#pragma unroll
            for (int q = 0; q < 16; q++) acc[q] = 0.0f;
#pragma unroll
            for (int ks = 0; ks < 6; ks++) {
                uint4v au = *(const uint4v*)(xS + e * XP + ks * 16 + half * 8);
                uint4v bu = *(const uint4v*)(nw1PL + ((size_t)(nt * 6 + ks) * 512 + lane * 8));
                acc = __builtin_amdgcn_mfma_f32_32x32x16_bf16(
                          __builtin_bit_cast(bf16x8, au),
                          __builtin_bit_cast(bf16x8, bu), acc, 0, 0, 0);
            }
            int o = nt * 32 + e;
            float b1 = nb1L[o];
#pragma unroll
            for (int q = 0; q < 16; q++) {
                int row = (q & 3) + 8 * (q >> 2) + 4 * half;
                hS[row * HP + o] = bf16_rn(silu_f(acc[q] + b1));
            }
        }
        __syncthreads();

        if (wave < 2) {
            int nt = wave;
            f32x16 acc;
#pragma unroll
            for (int q = 0; q < 16; q++) acc[q] = 0.0f;
#pragma unroll
            for (int ks = 0; ks < 8; ks++) {
                uint4v au = *(const uint4v*)(hS + e * HP + ks * 16 + half * 8);
                uint4v bu = *(const uint4v*)(nw2PL + ((size_t)(nt * 8 + ks) * 512 + lane * 8));
                acc = __builtin_amdgcn_mfma_f32_32x32x16_bf16(
                          __builtin_bit_cast(bf16x8, au),
                          __builtin_bit_cast(bf16x8, bu), acc, 0, 0, 0);
            }
            int o = nt * 32 + e;
            float b2 = nb2L[o];
#pragma unroll
            for (int q = 0; q < 16; q++) {
                int row = (q & 3) + 8 * (q >> 2) + 4 * half;
                float fo = acc[q] + b2 + bf16_up(xS[row * XP + o]);
                fOut[(size_t)(n0 + row) * DIM + o] = fo;
                xS[row * XP + o] = bf16_rn(fo);
            }
        }
        __syncthreads();
    }

    {
        uint4v afrag[4];
#pragma unroll
        for (int ks = 0; ks < 4; ks++)
            afrag[ks] = *(const uint4v*)(xS + e * XP + ks * 16 + half * 8);

        for (int nt = wave; nt < NTILE; nt += 4) {
            f32x16 acc;
#pragma unroll
            for (int q = 0; q < 16; q++) acc[q] = 0.0f;
#pragma unroll
            for (int ks = 0; ks < 4; ks++) {
                uint4v bu = *(const uint4v*)(ew1PL + ((size_t)(nt * 4 + ks) * 512 + lane * 8));
                acc = __builtin_amdgcn_mfma_f32_32x32x16_bf16(
                          __builtin_bit_cast(bf16x8, afrag[ks]),
                          __builtin_bit_cast(bf16x8, bu), acc, 0, 0, 0);
            }
            int o = nt * 32 + e;
            float eb = (o < EH) ? eb1L[o] : 0.0f;
            int col = (o < EH) ? o : (o + 14);
#pragma unroll
            for (int q = 0; q < 16; q++) {
                int row = (q & 3) + 8 * (q >> 2) + 4 * half;
                float v = (o < NOUT) ? (acc[q] + eb) : 0.0f;
                outS[row * OP + col] = bf16_rn(v);
            }
        }
    }
    __syncthreads();

    for (int x = tid; x < 32 * 68; x += 256) {
        int row = x / 68, off = x % 68;
        int gd = gdstS[row];
        uint4v v = *(const uint4v*)(outS + row * OP + off * 8);
        if (off < 34) *(uint4v*)(aH + (size_t)gd * KP + off * 8) = v;
        else          *(uint4v*)(bH + (size_t)gd * KP + (off - 34) * 8) = v;
    }
}

// ---------------------------------------------------------------------------
// MFMA edge kernel v4: RPW i-rows per wave (templated).
// Block = (group, 4*RPW-i-tile, 32-j-tile); shared per-k0 loads amortized
// over RPW MFMA chains.
// ---------------------------------------------------------------------------
template<int RPW>
__global__ __launch_bounds__(256)
void k_edge(const unsigned short* __restrict__ aH,
            const unsigned short* __restrict__ bH,
            const float* __restrict__ coorsO,
            const float* __restrict__ wdFL,
            const unsigned short* __restrict__ ew2PL,
            const float* __restrict__ eb2L,
            const unsigned short* __restrict__ cw1PL,
            const float* __restrict__ cbwPL,
            const float* __restrict__ cb2L,
            const float* __restrict__ lnbL,
            float* __restrict__ miBuf, float* __restrict__ deltaBuf,
            int Nn, int itpg, int njt) {
    constexpr int IR = 4 * RPW;
    __shared__ unsigned short bS[32 * BPITCH];
    __shared__ __align__(16) float aSf[IR * APITCH];
    __shared__ __align__(16) float wdS[KP];
    __shared__ float cjS[32 * 3];
    __shared__ __align__(16) float cbwS[256];
    __shared__ unsigned short mT[4][32 * 36];

    int bid = blockIdx.x;
    int g   = bid / (itpg * njt);
    int r   = bid % (itpg * njt);
    int it  = r / njt;
    int jt  = r % njt;

    int tid  = threadIdx.x;
    int wave = tid >> 6, lane = tid & 63, half = lane >> 5, e = lane & 31;

    int j0  = jt * 32;
    int njr = Nn - j0; if (njr > 32) njr = 32;
    int i0  = it * IR;
    int nir = Nn - i0; if (nir > IR) nir = IR;

    {
        const unsigned int* src = (const unsigned int*)(bH + (size_t)(g * Nn + j0) * KP);
        unsigned int* dst = (unsigned int*)bS;
        int tot = njr * 136;
        for (int x = tid; x < tot; x += 256) {
            int rr = x / 136, c = x % 136;
            dst[rr * (BPITCH / 2) + c] = src[rr * 136 + c];
        }
        const unsigned short* asrc = aH + (size_t)(g * Nn + i0) * KP;
        int at = nir * KP;
        for (int x = tid; x < at; x += 256) {
            int rr = x / KP, k = x % KP;
            aSf[rr * APITCH + k] = bf16_up(asrc[rr * KP + k]);
        }
        for (int x = tid; x < KP; x += 256) wdS[x] = wdFL[x];
        if (tid < njr * 3) cjS[tid] = coorsO[(g * Nn + j0) * 3 + tid];
        if (tid < 256) cbwS[tid] = cbwPL[tid];
    }
    __syncthreads();

    float eb2v = eb2L[e];
    float beta = lnbL[0];
    float cb2v = cb2L[0];

    int  jc     = (e < njr) ? e : (njr - 1);
    bool jvalid = (e < njr);
    float cjx = cjS[jc * 3 + 0], cjy = cjS[jc * 3 + 1], cjz = cjS[jc * 3 + 2];

    unsigned short* mW = &mT[wave][0];
    const unsigned short* bRow = bS + jc * BPITCH;

    bool  vA[RPW];
    int   giA[RPW];
    float rxA[RPW], ryA[RPW], rzA[RPW], ddA[RPW];
    const float* aR[RPW];
#pragma unroll
    for (int rr = 0; rr < RPW; rr++) {
        int il = wave * RPW + rr;
        vA[rr] = il < nir;
        int ilc = vA[rr] ? il : 0;
        giA[rr] = g * Nn + i0 + ilc;
        float cx = coorsO[giA[rr] * 3 + 0], cy = coorsO[giA[rr] * 3 + 1],
              cz = coorsO[giA[rr] * 3 + 2];
        rxA[rr] = cx - cjx; ryA[rr] = cy - cjy; rzA[rr] = cz - cjz;
        ddA[rr] = rxA[rr] * rxA[rr] + ryA[rr] * ryA[rr] + rzA[rr] * rzA[rr];
        aR[rr] = aSf + ilc * APITCH;
    }

    // ---- stage 2: merged K loop for RPW i-rows ----
    f32x16 acc[RPW];
#pragma unroll
    for (int rr = 0; rr < RPW; rr++)
#pragma unroll
        for (int q = 0; q < 16; q++) acc[rr][q] = 0.0f;

    for (int k0 = 0; k0 < NK0; k0++) {
        int ko = k0 * 16 + half * 8;
        uint2 bA = *(const uint2*)(bRow + ko);
        uint2 bB = *(const uint2*)(bRow + ko + 4);
        f32x4 wv0 = *(const f32x4*)(wdS + ko);
        f32x4 wv1 = *(const f32x4*)(wdS + ko + 4);
        uint4v eu = *(const uint4v*)(ew2PL + ((size_t)k0 * 64 + lane) * 8);
        f32x2 b2_0 = ub2(bA.x), b2_1 = ub2(bA.y), b2_2 = ub2(bB.x), b2_3 = ub2(bB.y);

#pragma unroll
        for (int rr = 0; rr < RPW; rr++) {
            f32x4 a0 = *(const f32x4*)(aR[rr] + ko);
            f32x4 a1 = *(const f32x4*)(aR[rr] + ko + 4);
            f32x2 d2 = mk2(ddA[rr], ddA[rr]);
            uint4v hu;
            hu[0] = hpack(a0.xy, wv0.xy, b2_0, d2);
            hu[1] = hpack(a0.zw, wv0.zw, b2_1, d2);
            hu[2] = hpack(a1.xy, wv1.xy, b2_2, d2);
            hu[3] = hpack(a1.zw, wv1.zw, b2_3, d2);
            acc[rr] = __builtin_amdgcn_mfma_f32_32x32x16_bf16(
                          __builtin_bit_cast(bf16x8, hu),
                          __builtin_bit_cast(bf16x8, eu), acc[rr], 0, 0, 0);
        }
    }

    f32x2 ebp = mk2(eb2v, eb2v);

#pragma unroll
    for (int s = 0; s < RPW; s++) {
        if (!vA[s]) continue;
        int gi = giA[s];
        float rx = rxA[s], ry = ryA[s], rz = rzA[s];
        float dist = ddA[s];

        // ---- stage 2 epilogue ----
        float mv[16];
        f32x2 mi2 = mk2(0.0f, 0.0f);
        if (njr == 32) {
#pragma unroll
            for (int qp = 0; qp < 8; qp++) {
                int q = qp * 2;
                f32x2 x2 = mk2(acc[s][q], acc[s][q + 1]) + ebp;
                f32x2 m2 = silu2(x2);
                mv[q] = m2.x; mv[q + 1] = m2.y;
                mi2 += m2;
            }
        } else {
#pragma unroll
            for (int qp = 0; qp < 8; qp++) {
                int q = qp * 2;
                f32x2 x2 = mk2(acc[s][q], acc[s][q + 1]) + ebp;
                f32x2 m2 = silu2(x2);
                int row0 = (q & 3) + 8 * (q >> 2) + 4 * half;
                if (j0 + row0 >= Nn) m2.x = 0.0f;
                if (j0 + row0 + 1 >= Nn) m2.y = 0.0f;
                mv[q] = m2.x; mv[q + 1] = m2.y;
                mi2 += m2;
            }
        }
        float miAcc = mi2.x + mi2.y;

#pragma unroll
        for (int q = 0; q < 4; q++) {
            unsigned lo = __builtin_amdgcn_perm(__float_as_uint(mv[q * 4 + 1]),
                                                __float_as_uint(mv[q * 4 + 0]), 0x07060302u);
            unsigned hi = __builtin_amdgcn_perm(__float_as_uint(mv[q * 4 + 3]),
                                                __float_as_uint(mv[q * 4 + 2]), 0x07060302u);
            int row0 = 8 * q + 4 * half;
            *(uint2*)&mW[e * 36 + row0] = make_uint2(lo, hi);
        }

        miAcc += __shfl_xor(miAcc, 32, 64);
        if (half == 0) atomicAdd(&miBuf[gi * MDIM + e], miAcc);

        // ---- stage 3 ----
        bf16x8 bq[2];
#pragma unroll
        for (int k0 = 0; k0 < 2; k0++) {
            uint4v t;
#pragma unroll
            for (int p = 0; p < 4; p++) {
                unsigned w0 = mW[(k0 * 16 + half * 8 + 2 * p    ) * 36 + e];
                unsigned w1 = mW[(k0 * 16 + half * 8 + 2 * p + 1) * 36 + e];
                t[p] = w0 | (w1 << 16);
            }
            bq[k0] = __builtin_bit_cast(bf16x8, t);
        }

        f32x2 w2a = mk2(0.0f, 0.0f);
#pragma unroll
        for (int mb = 0; mb < 4; mb++) {
            f32x16 sacc;
#pragma unroll
            for (int q = 0; q < 16; q++) sacc[q] = 0.0f;
#pragma unroll
            for (int k0 = 0; k0 < 2; k0++) {
                uint4v cu = *(const uint4v*)(cw1PL + ((size_t)(mb * 2 + k0) * 64 + lane) * 8);
                sacc = __builtin_amdgcn_mfma_f32_32x32x16_bf16(
                           __builtin_bit_cast(bf16x8, cu), bq[k0], sacc, 0, 0, 0);
            }
            const f32x4* cv = (const f32x4*)(cbwS + (half * 4 + mb) * 32);
#pragma unroll
            for (int qp = 0; qp < 8; qp++) {
                f32x4 c4 = cv[qp];
                f32x2 s2 = mk2(sacc[2 * qp], sacc[2 * qp + 1]) + mk2(c4.x, c4.z);
                f32x2 p2 = silu2(s2);
                w2a = __builtin_elementwise_fma(p2, mk2(c4.y, c4.w), w2a);
            }
        }
        float wAcc = w2a.x + w2a.y;
        wAcc += __shfl_xor(wAcc, 32, 64);
        float w = wAcc + cb2v;
        float nrm = sqrtf(dist);
        float scale = (w * 0.02f) * beta * __builtin_amdgcn_rcpf(fmaxf(nrm, 1e-8f));

        float dAx = 0.0f, dAy = 0.0f, dAz = 0.0f;
        if (jvalid && half == 0) {
            dAx = scale * rx; dAy = scale * ry; dAz = scale * rz;
        }
#pragma unroll
        for (int m = 16; m >= 1; m >>= 1) {
            dAx += __shfl_xor(dAx, m, 64);
            dAy += __shfl_xor(dAy, m, 64);
            dAz += __shfl_xor(dAz, m, 64);
        }
        if (lane == 0) {
            atomicAdd(&deltaBuf[gi * 3 + 0], dAx);
            atomicAdd(&deltaBuf[gi * 3 + 1], dAy);
            atomicAdd(&deltaBuf[gi * 3 + 2], dAz);
        }
    }
}

// ---------------------------------------------------------------------------
__global__ void k_fin(const float* __restrict__ co, const float* __restrict__ dl,
                      float* __restrict__ out) {
    int idx = blockIdx.x * blockDim.x + threadIdx.x;
    if (idx < NNODE * 3) {
        int gnode = idx / 3, c = idx % 3;
        int nf = inv_map(gnode, 1);   // layer 15 is along-l
        out[nf * 3 + c] = co[idx] + dl[idx];
    }
}

// ---------------------------------------------------------------------------
extern "C" void kernel_launch(void* const* d_in, const int* in_sizes, int n_in,
                              void* d_out, int out_size, void* d_ws, size_t ws_size,
                              hipStream_t stream) {
    (void)in_sizes; (void)n_in; (void)out_size; (void)ws_size;

    const int*   tokens  = (const int*)d_in[0];
    const float* cords   = (const float*)d_in[1];
    const float* tok_emb = (const float*)d_in[2];
    const float* pos_emb = (const float*)d_in[3];
    const float* ew1 = (const float*)d_in[4];
    const float* eb1 = (const float*)d_in[5];
    const float* ew2 = (const float*)d_in[6];
    const float* eb2 = (const float*)d_in[7];
    const float* cw1 = (const float*)d_in[8];
    const float* cb1 = (const float*)d_in[9];
    const float* cw2 = (const float*)d_in[10];
    const float* cb2 = (const float*)d_in[11];
    const float* nw1 = (const float*)d_in[12];
    const float* nb1 = (const float*)d_in[13];
    const float* nw2 = (const float*)d_in[14];
    const float* nb2 = (const float*)d_in[15];
    /* d_in[16] = ln_g : multiplied by zeros in the reference -> unused */
    const float* lnb = (const float*)d_in[17];

    float* wf = (float*)d_ws;
    float* featsA = wf; wf += NNODE * DIM;
    float* featsB = wf; wf += NNODE * DIM;
    float* coorsO0 = wf; wf += NNODE * 3;
    float* coorsO1 = wf; wf += NNODE * 3;
    float* mi0  = wf; wf += NNODE * MDIM;
    float* mi1  = wf; wf += NNODE * MDIM;
    float* dl0  = wf; wf += NNODE * 3;
    float* dl1  = wf; wf += NNODE * 3;
    float* cbwP = wf; wf += NLAY * 256;
    float* wdF  = wf; wf += NLAY * KP;

    uintptr_t p = (uintptr_t)wf; p = (p + 15) & ~(uintptr_t)15;
    unsigned short* wh = (unsigned short*)p;
    unsigned short* aHb  = wh; wh += (size_t)NNODE * KP;
    unsigned short* bHb  = wh; wh += (size_t)NNODE * KP;
    unsigned short* ew2P = wh; wh += NLAY * NK0 * 512;
    unsigned short* cw1P = wh; wh += NLAY * 4096;
    unsigned short* ew1P = wh; wh += (size_t)NLAY * NTILE * 4 * 512;
    unsigned short* nw1P = wh; wh += (size_t)NLAY * 4 * 6 * 512;
    unsigned short* nw2P = wh; wh += (size_t)NLAY * 2 * 8 * 512;

    float* coorsO[2] = {coorsO0, coorsO1};
    float* miB[2]    = {mi0, mi1};
    float* dlB[2]    = {dl0, dl1};

    int prepN = NLAY * NTILE * 4 * 512;
    k_prep<<<(prepN + 255) / 256, 256, 0, stream>>>(
        ew1, ew2, cw1, cb1, cw2, nw1, nw2,
        wdF, ew2P, cw1P, cbwP, ew1P, nw1P, nw2P);
    k_embed<<<(NNODE * DIM + 255) / 256, 256, 0, stream>>>(
        tokens, tok_emb, pos_emb, featsA);

    float* fCur = featsA; float* fNxt = featsB;

    k_np<<<NNODE / 32, 256, 0, stream>>>(
        fCur, cords, nullptr, nullptr,
        nullptr, nullptr, nullptr, nullptr,
        ew1P + 0, eb1 + 0,
        fNxt, coorsO[0], miB[0], dlB[0],
        aHb, bHb, 0, 0, 0);

    for (int L = 0; L < NLAY; L++) {
        int alongL = (L / 4) % 2;
        int idx  = L & 1;
        int Nn   = alongL ? LL : NN;
        int njt  = alongL ? 3 : 1;
        int groups = NNODE / Nn;

        if (alongL) {
            int itpg = (Nn + 15) / 16;   // RPW=4 -> 16 rows/block
            k_edge<4><<<groups * itpg * njt, 256, 0, stream>>>(
                aHb, bHb, coorsO[idx],
                wdF + L * KP, ew2P + (size_t)L * NK0 * 512, eb2 + L * MDIM,
                cw1P + (size_t)L * 4096, cbwP + (size_t)L * 256,
                cb2 + L, lnb + L, miB[idx], dlB[idx], Nn, itpg, njt);
        } else {
            int itpg = (Nn + 7) / 8;     // RPW=2 -> 8 rows/block
            k_edge<2><<<groups * itpg * njt, 256, 0, stream>>>(
                aHb, bHb, coorsO[idx],
                wdF + L * KP, ew2P + (size_t)L * NK0 * 512, eb2 + L * MDIM,
                cw1P + (size_t)L * 4096, cbwP + (size_t)L * 256,
                cb2 + L, lnb + L, miB[idx], dlB[idx], Nn, itpg, njt);
        }

        if (L < NLAY - 1) {
            int aL1 = ((L + 1) / 4) % 2;
            int nidx = (L + 1) & 1;
            k_np<<<NNODE / 32, 256, 0, stream>>>(
                fCur, coorsO[idx], miB[idx], dlB[idx],
                nw1P + (size_t)L * 4 * 6 * 512, nb1 + L * NH,
                nw2P + (size_t)L * 2 * 8 * 512, nb2 + L * DIM,
                ew1P + (size_t)(L + 1) * NTILE * 4 * 512, eb1 + (size_t)(L + 1) * EH,
                fNxt, coorsO[nidx], miB[nidx], dlB[nidx],
                aHb, bHb, alongL, aL1, 1);
            float* t = fCur; fCur = fNxt; fNxt = t;
        } else {
            k_fin<<<(NNODE * 3 + 255) / 256, 256, 0, stream>>>(
                coorsO[idx], dlB[idx], (float*)d_out);
        }
    }
}

// Round 9
// 962.447 us; speedup vs baseline: 1.1222x; 1.1222x over previous
//
#include <hip/hip_runtime.h>
#include <math.h>

#define DIM   64
#define MDIM  32
#define NLAY  16
#define PAD   1
#define NB    2
#define LL    96
#define NN    23
#define NNODE (NB*LL*NN)   /* 4416 */
#define EIN   129
#define EH    258          /* EIN*2 */
#define KP    272          /* EH padded to 17*16 */
#define NK0   17
#define NH    128          /* DIM*2 */
#define BPITCH 276         /* bS pitch shorts */
#define APITCH 276         /* aS pitch floats (16B rows) */
#define NT2   18           /* a: 9 tiles (288), b: 9 tiles (288) */
#define XP    104
#define HP    136
#define OPS   168          /* outS pitch shorts in split k_np (5*32 + 8) */

typedef __attribute__((ext_vector_type(8)))  short        bf16x8;
typedef __attribute__((ext_vector_type(16))) float        f32x16;
typedef __attribute__((ext_vector_type(4)))  unsigned int uint4v;
typedef __attribute__((ext_vector_type(2)))  float        f32x2;
typedef __attribute__((ext_vector_type(4)))  float        f32x4;

__device__ __forceinline__ f32x2 mk2(float a, float b) { f32x2 r; r.x = a; r.y = b; return r; }
__device__ __forceinline__ f32x4 mk4(float a, float b, float c, float d) {
    f32x4 r; r.x = a; r.y = b; r.z = c; r.w = d; return r;
}

__device__ __forceinline__ float silu_f(float x) {
    float e = __expf(-x);
    return x * __builtin_amdgcn_rcpf(1.0f + e);
}
// batched silu: 4 exp + 1 rcp per 4 elements (was 8 trans)
__device__ __forceinline__ f32x4 silu4(f32x4 x) {
    f32x4 t = x * (-1.44269504f);
    f32x4 e;
    e.x = __builtin_amdgcn_exp2f(t.x);
    e.y = __builtin_amdgcn_exp2f(t.y);
    e.z = __builtin_amdgcn_exp2f(t.z);
    e.w = __builtin_amdgcn_exp2f(t.w);
    f32x4 d = e + 1.0f;
    float p01 = d.x * d.y, p23 = d.z * d.w;
    float R = __builtin_amdgcn_rcpf(p01 * p23);
    float R01 = R * p23, R23 = R * p01;
    f32x4 sg;
    sg.x = d.y * R01; sg.y = d.x * R01;
    sg.z = d.w * R23; sg.w = d.z * R23;
    return x * sg;
}
__device__ __forceinline__ unsigned short bf16_rn(float x) {
    unsigned u = __float_as_uint(x);
    u += 0x7FFF + ((u >> 16) & 1);
    return (unsigned short)(u >> 16);
}
__device__ __forceinline__ float bf16_up(unsigned short h) {
    return __uint_as_float(((unsigned)h) << 16);
}
// H = silu(a + b + dist*wd) for 4 elems -> two bf16x2 words (by value)
__device__ __forceinline__ uint2 hpack4(f32x4 a4, f32x4 w4, unsigned bu0, unsigned bu1,
                                        float dist) {
    f32x4 b4;
    b4.x = __uint_as_float(bu0 << 16);
    b4.y = __uint_as_float(bu0 & 0xFFFF0000u);
    b4.z = __uint_as_float(bu1 << 16);
    b4.w = __uint_as_float(bu1 & 0xFFFF0000u);
    f32x4 x4 = a4 + b4;
    f32x4 d4 = mk4(dist, dist, dist, dist);
    x4 = __builtin_elementwise_fma(d4, w4, x4);
    f32x4 h4 = silu4(x4);
    uint2 o;
    o.x = __builtin_amdgcn_perm(__float_as_uint(h4.y), __float_as_uint(h4.x), 0x07060302u);
    o.y = __builtin_amdgcn_perm(__float_as_uint(h4.w), __float_as_uint(h4.z), 0x07060302u);
    return o;
}
__device__ __forceinline__ int fwd_map(int nf, int alongL) {
    if (alongL) {
        int b = nf / (LL * NN);
        int rem = nf % (LL * NN);
        int l = rem / NN, n = rem % NN;
        return (b * NN + n) * LL + l;
    }
    return nf;
}
__device__ __forceinline__ int inv_map(int gnode, int alongL) {
    if (alongL) {
        int g = gnode / LL, l = gnode % LL;
        int b = g / NN, n = g % NN;
        return (b * LL + l) * NN + n;
    }
    return gnode;
}

// ---------------------------------------------------------------------------
__global__ void k_embed(const int* __restrict__ tokens,
                        const float* __restrict__ tok_emb,
                        const float* __restrict__ pos_emb,
                        float* __restrict__ feats) {
    int idx = blockIdx.x * blockDim.x + threadIdx.x;
    if (idx < NNODE * DIM) {
        int node = idx / DIM, d = idx % DIM;
        int b = node / (LL * NN);
        int rem = node % (LL * NN);
        int n = rem % NN;
        int l = rem / NN;
        int t = tokens[b * LL + l];
        float f = tok_emb[t * DIM + d];
        if (t != PAD) f += pos_emb[(n + 2) * DIM + d];
        feats[idx] = f;
    }
}

// ---------------------------------------------------------------------------
__global__ void k_prep(const float* __restrict__ ew1, const float* __restrict__ ew2,
                       const float* __restrict__ cw1, const float* __restrict__ cb1,
                       const float* __restrict__ cw2,
                       const float* __restrict__ nw1, const float* __restrict__ nw2,
                       float* __restrict__ wdF, unsigned short* __restrict__ ew2P,
                       unsigned short* __restrict__ cw1P,
                       float* __restrict__ cbwP,
                       unsigned short* __restrict__ ew1P,
                       unsigned short* __restrict__ nw1P,
                       unsigned short* __restrict__ nw2P) {
    int idx = blockIdx.x * blockDim.x + threadIdx.x;
    if (idx < NLAY * KP) {
        int L = idx / KP, k = idx % KP;
        float v = (k < EH) ? ew1[(size_t)L * EIN * EH + 128 * EH + k] : 0.0f;
        wdF[idx] = bf16_up(bf16_rn(v));
    }
    if (idx < NLAY * NK0 * 512) {
        int L = idx / (NK0 * 512); int r = idx % (NK0 * 512);
        int k0 = r / 512; int r2 = r % 512;
        int lane = r2 >> 3, j = r2 & 7;
        int k = k0 * 16 + (lane >> 5) * 8 + j;
        int n = lane & 31;
        float v = (k < EH) ? ew2[((size_t)L * EH + k) * MDIM + n] : 0.0f;
        ew2P[idx] = bf16_rn(v);
    }
    if (idx < NLAY * 4096) {
        int L = idx / 4096; int r = idx % 4096;
        int mb = r / 1024; int r2 = r % 1024;
        int k0 = r2 / 512; int r3 = r2 % 512;
        int lane = r3 >> 3, j = r3 & 7;
        int k = k0 * 16 + (lane >> 5) * 8 + j;
        int o = mb * 32 + (lane & 31);
        cw1P[idx] = bf16_rn(cw1[((size_t)L * MDIM + k) * NH + o]);
    }
    if (idx < NLAY * 128) {
        int L = idx / 128; int r = idx % 128;
        int hlf = r / 64; int r2 = r % 64;
        int mb = r2 / 16, reg = r2 % 16;
        int o = mb * 32 + (reg & 3) + 8 * (reg >> 2) + 4 * hlf;
        cbwP[(size_t)L * 256 + r * 2 + 0] = cb1[L * NH + o];
        cbwP[(size_t)L * 256 + r * 2 + 1] = cw2[L * NH + o];
    }
    // ew1P: NT2=18 tiles; tiles 0-8 = a (c 0..287, real <258), 9-17 = b
    if (idx < NLAY * NT2 * 4 * 512) {
        int L = idx / (NT2 * 4 * 512); int r = idx % (NT2 * 4 * 512);
        int nt = r / 2048; int r2 = r % 2048;
        int ks = r2 / 512; int r3 = r2 % 512;
        int lane = r3 >> 3, j = r3 & 7;
        int d = ks * 16 + (lane >> 5) * 8 + j;
        int c = nt * 32 + (lane & 31);              // 0..575
        float v = 0.0f;
        if (c < 288) { if (c < EH) v = ew1[(size_t)L * EIN * EH + d * EH + c]; }
        else { int ob = c - 288; if (ob < EH) v = ew1[(size_t)L * EIN * EH + (DIM + d) * EH + ob]; }
        ew1P[idx] = bf16_rn(v);
    }
    if (idx < NLAY * 4 * 6 * 512) {
        int L = idx / 12288; int r = idx % 12288;
        int nt = r / 3072; int r2 = r % 3072;
        int ks = r2 / 512; int r3 = r2 % 512;
        int lane = r3 >> 3, j = r3 & 7;
        int k = ks * 16 + (lane >> 5) * 8 + j;
        int n = nt * 32 + (lane & 31);
        nw1P[idx] = bf16_rn(nw1[((size_t)L * (DIM + MDIM) + k) * NH + n]);
    }
    if (idx < NLAY * 2 * 8 * 512) {
        int L = idx / 8192; int r = idx % 8192;
        int nt = r / 4096; int r2 = r % 4096;
        int ks = r2 / 512; int r3 = r2 % 512;
        int lane = r3 >> 3, j = r3 & 7;
        int k = ks * 16 + (lane >> 5) * 8 + j;
        int n = nt * 32 + (lane & 31);
        nw2P[idx] = bf16_rn(nw2[((size_t)L * NH + k) * DIM + n]);
    }
}

// ---------------------------------------------------------------------------
// Fused node-MLP(L) + pre(L+1), 4-way N-split: grid = (NNODE/32)*4.
// ---------------------------------------------------------------------------
__global__ __launch_bounds__(256)
void k_np(const float* __restrict__ fIn, const float* __restrict__ coSrc,
          const float* __restrict__ miL, const float* __restrict__ dL,
          const unsigned short* __restrict__ nw1PL, const float* __restrict__ nb1L,
          const unsigned short* __restrict__ nw2PL, const float* __restrict__ nb2L,
          const unsigned short* __restrict__ ew1PL, const float* __restrict__ eb1L,
          float* __restrict__ fOut, float* __restrict__ coDst,
          float* __restrict__ miNext, float* __restrict__ dNext,
          unsigned short* __restrict__ aH, unsigned short* __restrict__ bH,
          int aL0, int aL1, int doNode) {
    __shared__ unsigned short xS[32 * XP];
    __shared__ unsigned short hS[32 * HP];
    __shared__ unsigned short outS[32 * OPS];
    __shared__ int gsrcS[32], gdstS[32];

    int bid  = blockIdx.x;
    int tileB = bid >> 2, par = bid & 3;
    int n0  = tileB * 32;
    int tid = threadIdx.x;
    int wave = tid >> 6, lane = tid & 63, half = lane >> 5, e = lane & 31;

    if (tid < 32) {
        gsrcS[tid] = fwd_map(n0 + tid, aL0);
        gdstS[tid] = fwd_map(n0 + tid, aL1);
    }
    __syncthreads();

    for (int i = 0; i < 8; i++) {
        int x = tid + 256 * i;
        int node = x >> 6, d = x & 63;
        xS[node * XP + d] = bf16_rn(fIn[(n0 + node) * DIM + d]);
    }
    if (doNode) {
        for (int i = 0; i < 4; i++) {
            int x = tid + 256 * i;
            int node = x >> 5, d = x & 31;
            xS[node * XP + DIM + d] = bf16_rn(miL[(size_t)gsrcS[node] * MDIM + d]);
        }
    }
    if (par == 0) {
        if (tid < 96) {
            int node = tid / 3, c = tid % 3;
            int gs = gsrcS[node], gd = gdstS[node];
            float cv = coSrc[gs * 3 + c] + (doNode ? dL[gs * 3 + c] : 0.0f);
            coDst[gd * 3 + c] = cv;
            dNext[gd * 3 + c] = 0.0f;
        }
        for (int i = 0; i < 4; i++) {
            int x = tid + 256 * i;
            int node = x >> 5, d = x & 31;
            miNext[(size_t)gdstS[node] * MDIM + d] = 0.0f;
        }
    }
    __syncthreads();

    if (doNode) {
        {
            int nt = wave;
            f32x16 acc;
#pragma unroll
            for (int q = 0; q < 16; q++) acc[q] = 0.0f;
#pragma unroll
            for (int ks = 0; ks < 6; ks++) {
                uint4v au = *(const uint4v*)(xS + e * XP + ks * 16 + half * 8);
                uint4v bu = *(const uint4v*)(nw1PL + ((size_t)(nt * 6 + ks) * 512 + lane * 8));
                acc = __builtin_amdgcn_mfma_f32_32x32x16_bf16(
                          __builtin_bit_cast(bf16x8, au),
                          __builtin_bit_cast(bf16x8, bu), acc, 0, 0, 0);
            }
            int o = nt * 32 + e;
            float b1 = nb1L[o];
#pragma unroll
            for (int q = 0; q < 16; q++) {
                int row = (q & 3) + 8 * (q >> 2) + 4 * half;
                hS[row * HP + o] = bf16_rn(silu_f(acc[q] + b1));
            }
        }
        __syncthreads();

        if (wave < 2) {
            int nt = wave;
            f32x16 acc;
#pragma unroll
            for (int q = 0; q < 16; q++) acc[q] = 0.0f;
#pragma unroll
            for (int ks = 0; ks < 8; ks++) {
                uint4v au = *(const uint4v*)(hS + e * HP + ks * 16 + half * 8);
                uint4v bu = *(const uint4v*)(nw2PL + ((size_t)(nt * 8 + ks) * 512 + lane * 8));
                acc = __builtin_amdgcn_mfma_f32_32x32x16_bf16(
                          __builtin_bit_cast(bf16x8, au),
                          __builtin_bit_cast(bf16x8, bu), acc, 0, 0, 0);
            }
            int o = nt * 32 + e;
            float b2 = nb2L[o];
#pragma unroll
            for (int q = 0; q < 16; q++) {
                int row = (q & 3) + 8 * (q >> 2) + 4 * half;
                float fo = acc[q] + b2 + bf16_up(xS[row * XP + o]);
                if (par == 0) fOut[(size_t)(n0 + row) * DIM + o] = fo;
                xS[row * XP + o] = bf16_rn(fo);
            }
        }
        __syncthreads();
    }

    // ---- GEMM3: this block's tiles nt = par + lt*4 ----
    {
        uint4v afrag[4];
#pragma unroll
        for (int ks = 0; ks < 4; ks++)
            afrag[ks] = *(const uint4v*)(xS + e * XP + ks * 16 + half * 8);

        for (int lt = wave; lt < 5; lt += 4) {
            int nt = par + lt * 4;
            if (nt >= NT2) continue;
            f32x16 acc;
#pragma unroll
            for (int q = 0; q < 16; q++) acc[q] = 0.0f;
#pragma unroll
            for (int ks = 0; ks < 4; ks++) {
                uint4v bu = *(const uint4v*)(ew1PL + ((size_t)(nt * 4 + ks) * 512 + lane * 8));
                acc = __builtin_amdgcn_mfma_f32_32x32x16_bf16(
                          __builtin_bit_cast(bf16x8, afrag[ks]),
                          __builtin_bit_cast(bf16x8, bu), acc, 0, 0, 0);
            }
            int c = nt * 32 + e;
            bool isA = c < 288;
            int oc = isA ? c : (c - 288);
            bool valid = oc < EH;
            float eb = (isA && valid) ? eb1L[oc] : 0.0f;
#pragma unroll
            for (int q = 0; q < 16; q++) {
                int row = (q & 3) + 8 * (q >> 2) + 4 * half;
                float v = valid ? (acc[q] + eb) : 0.0f;
                outS[row * OPS + lt * 32 + e] = bf16_rn(v);
            }
        }
    }
    __syncthreads();

    // ---- coalesced writeback of owned 16B chunks ----
    {
        int nch = (par < 2) ? 20 : 16;
        for (int x = tid; x < 32 * nch; x += 256) {
            int row = x / nch, cl = x % nch;
            int lt = cl >> 2, sub = cl & 3;
            int nt = par + lt * 4;
            uint4v v = *(const uint4v*)(outS + row * OPS + lt * 32 + sub * 8);
            int gd = gdstS[row];
            if (nt < 9) {
                int col = nt * 32 + sub * 8;
                if (col < KP) *(uint4v*)(aH + (size_t)gd * KP + col) = v;
            } else {
                int col = (nt - 9) * 32 + sub * 8;
                if (col < KP) *(uint4v*)(bH + (size_t)gd * KP + col) = v;
            }
        }
    }
}

// ---------------------------------------------------------------------------
// MFMA edge kernel (R6 structure: 2 i-rows/wave, lb(256,3)) + silu4.
// ---------------------------------------------------------------------------
__global__ __launch_bounds__(256, 3)
void k_edge(const unsigned short* __restrict__ aH,
            const unsigned short* __restrict__ bH,
            const float* __restrict__ coorsO,
            const float* __restrict__ wdFL,
            const unsigned short* __restrict__ ew2PL,
            const float* __restrict__ eb2L,
            const unsigned short* __restrict__ cw1PL,
            const float* __restrict__ cbwPL,
            const float* __restrict__ cb2L,
            const float* __restrict__ lnbL,
            float* __restrict__ miBuf, float* __restrict__ deltaBuf,
            int Nn, int itpg, int njt) {
    __shared__ unsigned short bS[32 * BPITCH];
    __shared__ __align__(16) float aSf[8 * APITCH];
    __shared__ __align__(16) float wdS[KP];
    __shared__ float cjS[32 * 3];
    __shared__ __align__(16) float cbwS[256];
    __shared__ unsigned short mT[4][32 * 36];

    int bid = blockIdx.x;
    int g   = bid / (itpg * njt);
    int r   = bid % (itpg * njt);
    int it  = r / njt;
    int jt  = r % njt;

    int tid  = threadIdx.x;
    int wave = tid >> 6, lane = tid & 63, half = lane >> 5, e = lane & 31;

    int j0  = jt * 32;
    int njr = Nn - j0; if (njr > 32) njr = 32;
    int i0  = it * 8;
    int nir = Nn - i0; if (nir > 8) nir = 8;

    {
        const unsigned int* src = (const unsigned int*)(bH + (size_t)(g * Nn + j0) * KP);
        unsigned int* dst = (unsigned int*)bS;
        int tot = njr * 136;
        for (int x = tid; x < tot; x += 256) {
            int rr = x / 136, c = x % 136;
            dst[rr * (BPITCH / 2) + c] = src[rr * 136 + c];
        }
        const unsigned short* asrc = aH + (size_t)(g * Nn + i0) * KP;
        int at = nir * KP;
        for (int x = tid; x < at; x += 256) {
            int rr = x / KP, k = x % KP;
            aSf[rr * APITCH + k] = bf16_up(asrc[rr * KP + k]);
        }
        for (int x = tid; x < KP; x += 256) wdS[x] = wdFL[x];
        if (tid < njr * 3) cjS[tid] = coorsO[(g * Nn + j0) * 3 + tid];
        if (tid < 256) cbwS[tid] = cbwPL[tid];
    }
    __syncthreads();

    float eb2v = eb2L[e];
    float beta = lnbL[0];
    float cb2v = cb2L[0];

    int  jc     = (e < njr) ? e : (njr - 1);
    bool jvalid = (e < njr);
    float cjx = cjS[jc * 3 + 0], cjy = cjS[jc * 3 + 1], cjz = cjS[jc * 3 + 2];

    unsigned short* mW = &mT[wave][0];
    const unsigned short* bRow = bS + jc * BPITCH;

    int il0 = wave * 2, il1 = wave * 2 + 1;
    bool v0 = il0 < nir, v1 = il1 < nir;
    int gi0 = g * Nn + i0 + (v0 ? il0 : 0);
    int gi1 = g * Nn + i0 + (v1 ? il1 : 0);

    float rx0, ry0, rz0, d0, rx1, ry1, rz1, d1;
    {
        float cx = coorsO[gi0 * 3 + 0], cy = coorsO[gi0 * 3 + 1], cz = coorsO[gi0 * 3 + 2];
        rx0 = cx - cjx; ry0 = cy - cjy; rz0 = cz - cjz;
        d0 = rx0 * rx0 + ry0 * ry0 + rz0 * rz0;
        cx = coorsO[gi1 * 3 + 0]; cy = coorsO[gi1 * 3 + 1]; cz = coorsO[gi1 * 3 + 2];
        rx1 = cx - cjx; ry1 = cy - cjy; rz1 = cz - cjz;
        d1 = rx1 * rx1 + ry1 * ry1 + rz1 * rz1;
    }
    const float* aR0 = aSf + (v0 ? il0 : 0) * APITCH;
    const float* aR1 = aSf + (v1 ? il1 : 0) * APITCH;

    f32x16 acc0, acc1;
#pragma unroll
    for (int q = 0; q < 16; q++) { acc0[q] = 0.0f; acc1[q] = 0.0f; }

#pragma unroll
    for (int k0 = 0; k0 < NK0; k0++) {
        int ko = k0 * 16 + half * 8;
        uint2 bA = *(const uint2*)(bRow + ko);
        uint2 bB = *(const uint2*)(bRow + ko + 4);
        f32x4 wv0 = *(const f32x4*)(wdS + ko);
        f32x4 wv1 = *(const f32x4*)(wdS + ko + 4);
        uint4v eu = *(const uint4v*)(ew2PL + ((size_t)k0 * 64 + lane) * 8);

        f32x4 a00 = *(const f32x4*)(aR0 + ko);
        f32x4 a01 = *(const f32x4*)(aR0 + ko + 4);
        uint2 h00 = hpack4(a00, wv0, bA.x, bA.y, d0);
        uint2 h01 = hpack4(a01, wv1, bB.x, bB.y, d0);
        uint4v hu0;
        hu0[0] = h00.x; hu0[1] = h00.y; hu0[2] = h01.x; hu0[3] = h01.y;
        acc0 = __builtin_amdgcn_mfma_f32_32x32x16_bf16(
                   __builtin_bit_cast(bf16x8, hu0),
                   __builtin_bit_cast(bf16x8, eu), acc0, 0, 0, 0);

        f32x4 a10 = *(const f32x4*)(aR1 + ko);
        f32x4 a11 = *(const f32x4*)(aR1 + ko + 4);
        uint2 h10 = hpack4(a10, wv0, bA.x, bA.y, d1);
        uint2 h11 = hpack4(a11, wv1, bB.x, bB.y, d1);
        uint4v hu1;
        hu1[0] = h10.x; hu1[1] = h10.y; hu1[2] = h11.x; hu1[3] = h11.y;
        acc1 = __builtin_amdgcn_mfma_f32_32x32x16_bf16(
                   __builtin_bit_cast(bf16x8, hu1),
                   __builtin_bit_cast(bf16x8, eu), acc1, 0, 0, 0);
    }

#pragma unroll
    for (int s = 0; s < 2; s++) {
        if (!(s ? v1 : v0)) continue;
        int gi = s ? gi1 : gi0;
        float rx = s ? rx1 : rx0, ry = s ? ry1 : ry0, rz = s ? rz1 : rz0;
        float dist = s ? d1 : d0;

        // ---- stage 2 epilogue: m = silu(acc+eb2), masked; m_i; stage m^T ----
        float mv[16];
        f32x4 mi4 = mk4(0.0f, 0.0f, 0.0f, 0.0f);
#pragma unroll
        for (int qg = 0; qg < 4; qg++) {
            int q = qg * 4;
            f32x4 x4 = mk4(s ? acc1[q] : acc0[q], s ? acc1[q + 1] : acc0[q + 1],
                           s ? acc1[q + 2] : acc0[q + 2], s ? acc1[q + 3] : acc0[q + 3])
                       + eb2v;
            f32x4 m4 = silu4(x4);
            if (njr != 32) {
                int row0 = 8 * qg + 4 * half;
                if (j0 + row0 + 0 >= Nn) m4.x = 0.0f;
                if (j0 + row0 + 1 >= Nn) m4.y = 0.0f;
                if (j0 + row0 + 2 >= Nn) m4.z = 0.0f;
                if (j0 + row0 + 3 >= Nn) m4.w = 0.0f;
            }
            mv[q] = m4.x; mv[q + 1] = m4.y; mv[q + 2] = m4.z; mv[q + 3] = m4.w;
            mi4 += m4;
        }
        float miAcc = (mi4.x + mi4.y) + (mi4.z + mi4.w);

#pragma unroll
        for (int q = 0; q < 4; q++) {
            unsigned lo = __builtin_amdgcn_perm(__float_as_uint(mv[q * 4 + 1]),
                                                __float_as_uint(mv[q * 4 + 0]), 0x07060302u);
            unsigned hi = __builtin_amdgcn_perm(__float_as_uint(mv[q * 4 + 3]),
                                                __float_as_uint(mv[q * 4 + 2]), 0x07060302u);
            int row0 = 8 * q + 4 * half;
            *(uint2*)&mW[e * 36 + row0] = make_uint2(lo, hi);
        }

        miAcc += __shfl_xor(miAcc, 32, 64);
        if (half == 0) atomicAdd(&miBuf[gi * MDIM + e], miAcc);

        // ---- stage 3 ----
        bf16x8 bq[2];
#pragma unroll
        for (int k0 = 0; k0 < 2; k0++) {
            uint4v t;
#pragma unroll
            for (int p = 0; p < 4; p++) {
                unsigned w0 = mW[(k0 * 16 + half * 8 + 2 * p    ) * 36 + e];
                unsigned w1 = mW[(k0 * 16 + half * 8 + 2 * p + 1) * 36 + e];
                t[p] = w0 | (w1 << 16);
            }
            bq[k0] = __builtin_bit_cast(bf16x8, t);
        }

        f32x4 w4a = mk4(0.0f, 0.0f, 0.0f, 0.0f);
#pragma unroll
        for (int mb = 0; mb < 4; mb++) {
            f32x16 sacc;
#pragma unroll
            for (int q = 0; q < 16; q++) sacc[q] = 0.0f;
#pragma unroll
            for (int k0 = 0; k0 < 2; k0++) {
                uint4v cu = *(const uint4v*)(cw1PL + ((size_t)(mb * 2 + k0) * 64 + lane) * 8);
                sacc = __builtin_amdgcn_mfma_f32_32x32x16_bf16(
                           __builtin_bit_cast(bf16x8, cu), bq[k0], sacc, 0, 0, 0);
            }
            const f32x4* cv = (const f32x4*)(cbwS + (half * 4 + mb) * 32);
#pragma unroll
            for (int i = 0; i < 4; i++) {
                f32x4 c0 = cv[2 * i], c1 = cv[2 * i + 1];
                f32x4 x4 = mk4(sacc[4 * i] + c0.x, sacc[4 * i + 1] + c0.z,
                               sacc[4 * i + 2] + c1.x, sacc[4 * i + 3] + c1.z);
                f32x4 p4 = silu4(x4);
                w4a = __builtin_elementwise_fma(p4, mk4(c0.y, c0.w, c1.y, c1.w), w4a);
            }
        }
        float wAcc = (w4a.x + w4a.y) + (w4a.z + w4a.w);
        wAcc += __shfl_xor(wAcc, 32, 64);
        float w = wAcc + cb2v;
        float nrm = sqrtf(dist);
        float scale = (w * 0.02f) * beta * __builtin_amdgcn_rcpf(fmaxf(nrm, 1e-8f));

        float dAx = 0.0f, dAy = 0.0f, dAz = 0.0f;
        if (jvalid && half == 0) {
            dAx = scale * rx; dAy = scale * ry; dAz = scale * rz;
        }
#pragma unroll
        for (int m = 16; m >= 1; m >>= 1) {
            dAx += __shfl_xor(dAx, m, 64);
            dAy += __shfl_xor(dAy, m, 64);
            dAz += __shfl_xor(dAz, m, 64);
        }
        if (lane == 0) {
            atomicAdd(&deltaBuf[gi * 3 + 0], dAx);
            atomicAdd(&deltaBuf[gi * 3 + 1], dAy);
            atomicAdd(&deltaBuf[gi * 3 + 2], dAz);
        }
    }
}

// ---------------------------------------------------------------------------
__global__ void k_fin(const float* __restrict__ co, const float* __restrict__ dl,
                      float* __restrict__ out) {
    int idx = blockIdx.x * blockDim.x + threadIdx.x;
    if (idx < NNODE * 3) {
        int gnode = idx / 3, c = idx % 3;
        int nf = inv_map(gnode, 1);   // layer 15 is along-l
        out[nf * 3 + c] = co[idx] + dl[idx];
    }
}

// ---------------------------------------------------------------------------
extern "C" void kernel_launch(void* const* d_in, const int* in_sizes, int n_in,
                              void* d_out, int out_size, void* d_ws, size_t ws_size,
                              hipStream_t stream) {
    (void)in_sizes; (void)n_in; (void)out_size; (void)ws_size;

    const int*   tokens  = (const int*)d_in[0];
    const float* cords   = (const float*)d_in[1];
    const float* tok_emb = (const float*)d_in[2];
    const float* pos_emb = (const float*)d_in[3];
    const float* ew1 = (const float*)d_in[4];
    const float* eb1 = (const float*)d_in[5];
    const float* ew2 = (const float*)d_in[6];
    const float* eb2 = (const float*)d_in[7];
    const float* cw1 = (const float*)d_in[8];
    const float* cb1 = (const float*)d_in[9];
    const float* cw2 = (const float*)d_in[10];
    const float* cb2 = (const float*)d_in[11];
    const float* nw1 = (const float*)d_in[12];
    const float* nb1 = (const float*)d_in[13];
    const float* nw2 = (const float*)d_in[14];
    const float* nb2 = (const float*)d_in[15];
    /* d_in[16] = ln_g : multiplied by zeros in the reference -> unused */
    const float* lnb = (const float*)d_in[17];

    float* wf = (float*)d_ws;
    float* featsA = wf; wf += NNODE * DIM;
    float* featsB = wf; wf += NNODE * DIM;
    float* coorsO0 = wf; wf += NNODE * 3;
    float* coorsO1 = wf; wf += NNODE * 3;
    float* mi0  = wf; wf += NNODE * MDIM;
    float* mi1  = wf; wf += NNODE * MDIM;
    float* dl0  = wf; wf += NNODE * 3;
    float* dl1  = wf; wf += NNODE * 3;
    float* cbwP = wf; wf += NLAY * 256;
    float* wdF  = wf; wf += NLAY * KP;

    uintptr_t p = (uintptr_t)wf; p = (p + 15) & ~(uintptr_t)15;
    unsigned short* wh = (unsigned short*)p;
    unsigned short* aHb  = wh; wh += (size_t)NNODE * KP;
    unsigned short* bHb  = wh; wh += (size_t)NNODE * KP;
    unsigned short* ew2P = wh; wh += NLAY * NK0 * 512;
    unsigned short* cw1P = wh; wh += NLAY * 4096;
    unsigned short* ew1P = wh; wh += (size_t)NLAY * NT2 * 4 * 512;
    unsigned short* nw1P = wh; wh += (size_t)NLAY * 4 * 6 * 512;
    unsigned short* nw2P = wh; wh += (size_t)NLAY * 2 * 8 * 512;

    float* coorsO[2] = {coorsO0, coorsO1};
    float* miB[2]    = {mi0, mi1};
    float* dlB[2]    = {dl0, dl1};

    int prepN = NLAY * NT2 * 4 * 512;
    k_prep<<<(prepN + 255) / 256, 256, 0, stream>>>(
        ew1, ew2, cw1, cb1, cw2, nw1, nw2,
        wdF, ew2P, cw1P, cbwP, ew1P, nw1P, nw2P);
    k_embed<<<(NNODE * DIM + 255) / 256, 256, 0, stream>>>(
        tokens, tok_emb, pos_emb, featsA);

    float* fCur = featsA; float* fNxt = featsB;

    k_np<<<(NNODE / 32) * 4, 256, 0, stream>>>(
        fCur, cords, nullptr, nullptr,
        nullptr, nullptr, nullptr, nullptr,
        ew1P + 0, eb1 + 0,
        fNxt, coorsO[0], miB[0], dlB[0],
        aHb, bHb, 0, 0, 0);

    for (int L = 0; L < NLAY; L++) {
        int alongL = (L / 4) % 2;
        int idx  = L & 1;
        int Nn   = alongL ? LL : NN;
        int njt  = alongL ? 3 : 1;
        int itpg = (Nn + 7) / 8;
        int groups = NNODE / Nn;

        k_edge<<<groups * itpg * njt, 256, 0, stream>>>(
            aHb, bHb, coorsO[idx],
            wdF + L * KP, ew2P + (size_t)L * NK0 * 512, eb2 + L * MDIM,
            cw1P + (size_t)L * 4096, cbwP + (size_t)L * 256,
            cb2 + L, lnb + L, miB[idx], dlB[idx], Nn, itpg, njt);

        if (L < NLAY - 1) {
            int aL1 = ((L + 1) / 4) % 2;
            int nidx = (L + 1) & 1;
            k_np<<<(NNODE / 32) * 4, 256, 0, stream>>>(
                fCur, coorsO[idx], miB[idx], dlB[idx],
                nw1P + (size_t)L * 4 * 6 * 512, nb1 + L * NH,
                nw2P + (size_t)L * 2 * 8 * 512, nb2 + L * DIM,
                ew1P + (size_t)(L + 1) * NT2 * 4 * 512, eb1 + (size_t)(L + 1) * EH,
                fNxt, coorsO[nidx], miB[nidx], dlB[nidx],
                aHb, bHb, alongL, aL1, 1);
            float* t = fCur; fCur = fNxt; fNxt = t;
        } else {
            k_fin<<<(NNODE * 3 + 255) / 256, 256, 0, stream>>>(
                coorsO[idx], dlB[idx], (float*)d_out);
        }
    }
}

// Round 10
// 932.070 us; speedup vs baseline: 1.1587x; 1.0326x over previous
//
#include <hip/hip_runtime.h>
#include <math.h>

#define DIM   64
#define MDIM  32
#define NLAY  16
#define PAD   1
#define NB    2
#define LL    96
#define NN    23
#define NNODE (NB*LL*NN)   /* 4416 */
#define EIN   129
#define EH    258          /* EIN*2 */
#define KP    272          /* EH padded to 17*16 */
#define NK0   17
#define NH    128          /* DIM*2 */
#define BPITCH 276         /* bS pitch shorts */
#define APITCH 276         /* aS pitch floats (16B rows) */
#define NT2   18           /* a: 9 tiles (288), b: 9 tiles (288) */
#define XP    104
#define HP    136
#define OPS   168          /* outS pitch shorts in split k_np */

typedef __attribute__((ext_vector_type(8)))  short        bf16x8;
typedef __attribute__((ext_vector_type(16))) float        f32x16;
typedef __attribute__((ext_vector_type(4)))  unsigned int uint4v;
typedef __attribute__((ext_vector_type(2)))  float        f32x2;
typedef __attribute__((ext_vector_type(4)))  float        f32x4;

__device__ __forceinline__ f32x2 mk2(float a, float b) { f32x2 r; r.x = a; r.y = b; return r; }

__device__ __forceinline__ float silu_f(float x) {
    float e = __expf(-x);
    return x * __builtin_amdgcn_rcpf(1.0f + e);
}
// packed silu: independent rcp per pair (shallow dependency chain — R6 winner)
__device__ __forceinline__ f32x2 silu2(f32x2 x) {
    f32x2 t = x * (-1.44269504f);
    f32x2 e;
    e.x = __builtin_amdgcn_exp2f(t.x);
    e.y = __builtin_amdgcn_exp2f(t.y);
    f32x2 den = e + 1.0f;
    f32x2 r;
    r.x = __builtin_amdgcn_rcpf(den.x);
    r.y = __builtin_amdgcn_rcpf(den.y);
    return x * r;
}
__device__ __forceinline__ unsigned short bf16_rn(float x) {
    unsigned u = __float_as_uint(x);
    u += 0x7FFF + ((u >> 16) & 1);
    return (unsigned short)(u >> 16);
}
__device__ __forceinline__ float bf16_up(unsigned short h) {
    return __uint_as_float(((unsigned)h) << 16);
}
__device__ __forceinline__ f32x2 ub2(unsigned bw) {
    return mk2(__uint_as_float(bw << 16), __uint_as_float(bw & 0xFFFF0000u));
}
__device__ __forceinline__ unsigned hpack(f32x2 a2, f32x2 w2, f32x2 b2, f32x2 d2) {
    f32x2 x2 = a2 + b2;
    x2 = __builtin_elementwise_fma(d2, w2, x2);
    f32x2 h2 = silu2(x2);
    return __builtin_amdgcn_perm(__float_as_uint(h2.y), __float_as_uint(h2.x), 0x07060302u);
}
__device__ __forceinline__ int fwd_map(int nf, int alongL) {
    if (alongL) {
        int b = nf / (LL * NN);
        int rem = nf % (LL * NN);
        int l = rem / NN, n = rem % NN;
        return (b * NN + n) * LL + l;
    }
    return nf;
}
__device__ __forceinline__ int inv_map(int gnode, int alongL) {
    if (alongL) {
        int g = gnode / LL, l = gnode % LL;
        int b = g / NN, n = g % NN;
        return (b * LL + l) * NN + n;
    }
    return gnode;
}

// ---------------------------------------------------------------------------
__global__ void k_embed(const int* __restrict__ tokens,
                        const float* __restrict__ tok_emb,
                        const float* __restrict__ pos_emb,
                        float* __restrict__ feats) {
    int idx = blockIdx.x * blockDim.x + threadIdx.x;
    if (idx < NNODE * DIM) {
        int node = idx / DIM, d = idx % DIM;
        int b = node / (LL * NN);
        int rem = node % (LL * NN);
        int n = rem % NN;
        int l = rem / NN;
        int t = tokens[b * LL + l];
        float f = tok_emb[t * DIM + d];
        if (t != PAD) f += pos_emb[(n + 2) * DIM + d];
        feats[idx] = f;
    }
}

// ---------------------------------------------------------------------------
__global__ void k_prep(const float* __restrict__ ew1, const float* __restrict__ ew2,
                       const float* __restrict__ cw1, const float* __restrict__ cb1,
                       const float* __restrict__ cw2,
                       const float* __restrict__ nw1, const float* __restrict__ nw2,
                       float* __restrict__ wdF, unsigned short* __restrict__ ew2P,
                       unsigned short* __restrict__ cw1P,
                       float* __restrict__ cbwP,
                       unsigned short* __restrict__ ew1P,
                       unsigned short* __restrict__ nw1P,
                       unsigned short* __restrict__ nw2P) {
    int idx = blockIdx.x * blockDim.x + threadIdx.x;
    if (idx < NLAY * KP) {
        int L = idx / KP, k = idx % KP;
        float v = (k < EH) ? ew1[(size_t)L * EIN * EH + 128 * EH + k] : 0.0f;
        wdF[idx] = bf16_up(bf16_rn(v));
    }
    if (idx < NLAY * NK0 * 512) {
        int L = idx / (NK0 * 512); int r = idx % (NK0 * 512);
        int k0 = r / 512; int r2 = r % 512;
        int lane = r2 >> 3, j = r2 & 7;
        int k = k0 * 16 + (lane >> 5) * 8 + j;
        int n = lane & 31;
        float v = (k < EH) ? ew2[((size_t)L * EH + k) * MDIM + n] : 0.0f;
        ew2P[idx] = bf16_rn(v);
    }
    if (idx < NLAY * 4096) {
        int L = idx / 4096; int r = idx % 4096;
        int mb = r / 1024; int r2 = r % 1024;
        int k0 = r2 / 512; int r3 = r2 % 512;
        int lane = r3 >> 3, j = r3 & 7;
        int k = k0 * 16 + (lane >> 5) * 8 + j;
        int o = mb * 32 + (lane & 31);
        cw1P[idx] = bf16_rn(cw1[((size_t)L * MDIM + k) * NH + o]);
    }
    if (idx < NLAY * 128) {
        int L = idx / 128; int r = idx % 128;
        int hlf = r / 64; int r2 = r % 64;
        int mb = r2 / 16, reg = r2 % 16;
        int o = mb * 32 + (reg & 3) + 8 * (reg >> 2) + 4 * hlf;
        cbwP[(size_t)L * 256 + r * 2 + 0] = cb1[L * NH + o];
        cbwP[(size_t)L * 256 + r * 2 + 1] = cw2[L * NH + o];
    }
    // ew1P: NT2=18 tiles; tiles 0-8 = a (c 0..287, real <258), 9-17 = b
    if (idx < NLAY * NT2 * 4 * 512) {
        int L = idx / (NT2 * 4 * 512); int r = idx % (NT2 * 4 * 512);
        int nt = r / 2048; int r2 = r % 2048;
        int ks = r2 / 512; int r3 = r2 % 512;
        int lane = r3 >> 3, j = r3 & 7;
        int d = ks * 16 + (lane >> 5) * 8 + j;
        int c = nt * 32 + (lane & 31);              // 0..575
        float v = 0.0f;
        if (c < 288) { if (c < EH) v = ew1[(size_t)L * EIN * EH + d * EH + c]; }
        else { int ob = c - 288; if (ob < EH) v = ew1[(size_t)L * EIN * EH + (DIM + d) * EH + ob]; }
        ew1P[idx] = bf16_rn(v);
    }
    if (idx < NLAY * 4 * 6 * 512) {
        int L = idx / 12288; int r = idx % 12288;
        int nt = r / 3072; int r2 = r % 3072;
        int ks = r2 / 512; int r3 = r2 % 512;
        int lane = r3 >> 3, j = r3 & 7;
        int k = ks * 16 + (lane >> 5) * 8 + j;
        int n = nt * 32 + (lane & 31);
        nw1P[idx] = bf16_rn(nw1[((size_t)L * (DIM + MDIM) + k) * NH + n]);
    }
    if (idx < NLAY * 2 * 8 * 512) {
        int L = idx / 8192; int r = idx % 8192;
        int nt = r / 4096; int r2 = r % 4096;
        int ks = r2 / 512; int r3 = r2 % 512;
        int lane = r3 >> 3, j = r3 & 7;
        int k = ks * 16 + (lane >> 5) * 8 + j;
        int n = nt * 32 + (lane & 31);
        nw2P[idx] = bf16_rn(nw2[((size_t)L * NH + k) * DIM + n]);
    }
}

// ---------------------------------------------------------------------------
// Fused node-MLP(L) + pre(L+1), 4-way N-split: grid = (NNODE/32)*4.
// ---------------------------------------------------------------------------
__global__ __launch_bounds__(256)
void k_np(const float* __restrict__ fIn, const float* __restrict__ coSrc,
          const float* __restrict__ miL, const float* __restrict__ dL,
          const unsigned short* __restrict__ nw1PL, const float* __restrict__ nb1L,
          const unsigned short* __restrict__ nw2PL, const float* __restrict__ nb2L,
          const unsigned short* __restrict__ ew1PL, const float* __restrict__ eb1L,
          float* __restrict__ fOut, float* __restrict__ coDst,
          float* __restrict__ miNext, float* __restrict__ dNext,
          unsigned short* __restrict__ aH, unsigned short* __restrict__ bH,
          int aL0, int aL1, int doNode) {
    __shared__ unsigned short xS[32 * XP];
    __shared__ unsigned short hS[32 * HP];
    __shared__ unsigned short outS[32 * OPS];
    __shared__ int gsrcS[32], gdstS[32];

    int bid  = blockIdx.x;
    int tileB = bid >> 2, par = bid & 3;
    int n0  = tileB * 32;
    int tid = threadIdx.x;
    int wave = tid >> 6, lane = tid & 63, half = lane >> 5, e = lane & 31;

    if (tid < 32) {
        gsrcS[tid] = fwd_map(n0 + tid, aL0);
        gdstS[tid] = fwd_map(n0 + tid, aL1);
    }
    __syncthreads();

    for (int i = 0; i < 8; i++) {
        int x = tid + 256 * i;
        int node = x >> 6, d = x & 63;
        xS[node * XP + d] = bf16_rn(fIn[(n0 + node) * DIM + d]);
    }
    if (doNode) {
        for (int i = 0; i < 4; i++) {
            int x = tid + 256 * i;
            int node = x >> 5, d = x & 31;
            xS[node * XP + DIM + d] = bf16_rn(miL[(size_t)gsrcS[node] * MDIM + d]);
        }
    }
    if (par == 0) {
        if (tid < 96) {
            int node = tid / 3, c = tid % 3;
            int gs = gsrcS[node], gd = gdstS[node];
            float cv = coSrc[gs * 3 + c] + (doNode ? dL[gs * 3 + c] : 0.0f);
            coDst[gd * 3 + c] = cv;
            dNext[gd * 3 + c] = 0.0f;
        }
        for (int i = 0; i < 4; i++) {
            int x = tid + 256 * i;
            int node = x >> 5, d = x & 31;
            miNext[(size_t)gdstS[node] * MDIM + d] = 0.0f;
        }
    }
    __syncthreads();

    if (doNode) {
        {
            int nt = wave;
            f32x16 acc;
#pragma unroll
            for (int q = 0; q < 16; q++) acc[q] = 0.0f;
#pragma unroll
            for (int ks = 0; ks < 6; ks++) {
                uint4v au = *(const uint4v*)(xS + e * XP + ks * 16 + half * 8);
                uint4v bu = *(const uint4v*)(nw1PL + ((size_t)(nt * 6 + ks) * 512 + lane * 8));
                acc = __builtin_amdgcn_mfma_f32_32x32x16_bf16(
                          __builtin_bit_cast(bf16x8, au),
                          __builtin_bit_cast(bf16x8, bu), acc, 0, 0, 0);
            }
            int o = nt * 32 + e;
            float b1 = nb1L[o];
#pragma unroll
            for (int q = 0; q < 16; q++) {
                int row = (q & 3) + 8 * (q >> 2) + 4 * half;
                hS[row * HP + o] = bf16_rn(silu_f(acc[q] + b1));
            }
        }
        __syncthreads();

        if (wave < 2) {
            int nt = wave;
            f32x16 acc;
#pragma unroll
            for (int q = 0; q < 16; q++) acc[q] = 0.0f;
#pragma unroll
            for (int ks = 0; ks < 8; ks++) {
                uint4v au = *(const uint4v*)(hS + e * HP + ks * 16 + half * 8);
                uint4v bu = *(const uint4v*)(nw2PL + ((size_t)(nt * 8 + ks) * 512 + lane * 8));
                acc = __builtin_amdgcn_mfma_f32_32x32x16_bf16(
                          __builtin_bit_cast(bf16x8, au),
                          __builtin_bit_cast(bf16x8, bu), acc, 0, 0, 0);
            }
            int o = nt * 32 + e;
            float b2 = nb2L[o];
#pragma unroll
            for (int q = 0; q < 16; q++) {
                int row = (q & 3) + 8 * (q >> 2) + 4 * half;
                float fo = acc[q] + b2 + bf16_up(xS[row * XP + o]);
                if (par == 0) fOut[(size_t)(n0 + row) * DIM + o] = fo;
                xS[row * XP + o] = bf16_rn(fo);
            }
        }
        __syncthreads();
    }

    // ---- GEMM3: this block's tiles nt = par + lt*4 ----
    {
        uint4v afrag[4];
#pragma unroll
        for (int ks = 0; ks < 4; ks++)
            afrag[ks] = *(const uint4v*)(xS + e * XP + ks * 16 + half * 8);

        for (int lt = wave; lt < 5; lt += 4) {
            int nt = par + lt * 4;
            if (nt >= NT2) continue;
            f32x16 acc;
#pragma unroll
            for (int q = 0; q < 16; q++) acc[q] = 0.0f;
#pragma unroll
            for (int ks = 0; ks < 4; ks++) {
                uint4v bu = *(const uint4v*)(ew1PL + ((size_t)(nt * 4 + ks) * 512 + lane * 8));
                acc = __builtin_amdgcn_mfma_f32_32x32x16_bf16(
                          __builtin_bit_cast(bf16x8, afrag[ks]),
                          __builtin_bit_cast(bf16x8, bu), acc, 0, 0, 0);
            }
            int c = nt * 32 + e;
            bool isA = c < 288;
            int oc = isA ? c : (c - 288);
            bool valid = oc < EH;
            float eb = (isA && valid) ? eb1L[oc] : 0.0f;
#pragma unroll
            for (int q = 0; q < 16; q++) {
                int row = (q & 3) + 8 * (q >> 2) + 4 * half;
                float v = valid ? (acc[q] + eb) : 0.0f;
                outS[row * OPS + lt * 32 + e] = bf16_rn(v);
            }
        }
    }
    __syncthreads();

    // ---- coalesced writeback of owned 16B chunks ----
    {
        int nch = (par < 2) ? 20 : 16;
        for (int x = tid; x < 32 * nch; x += 256) {
            int row = x / nch, cl = x % nch;
            int lt = cl >> 2, sub = cl & 3;
            int nt = par + lt * 4;
            uint4v v = *(const uint4v*)(outS + row * OPS + lt * 32 + sub * 8);
            int gd = gdstS[row];
            if (nt < 9) {
                int col = nt * 32 + sub * 8;
                if (col < KP) *(uint4v*)(aH + (size_t)gd * KP + col) = v;
            } else {
                int col = (nt - 9) * 32 + sub * 8;
                if (col < KP) *(uint4v*)(bH + (size_t)gd * KP + col) = v;
            }
        }
    }
}

// ---------------------------------------------------------------------------
// MFMA edge kernel — R6 version verbatim (silu2, merged 2-i-row K loop).
// ---------------------------------------------------------------------------
__global__ __launch_bounds__(256, 3)
void k_edge(const unsigned short* __restrict__ aH,
            const unsigned short* __restrict__ bH,
            const float* __restrict__ coorsO,
            const float* __restrict__ wdFL,
            const unsigned short* __restrict__ ew2PL,
            const float* __restrict__ eb2L,
            const unsigned short* __restrict__ cw1PL,
            const float* __restrict__ cbwPL,
            const float* __restrict__ cb2L,
            const float* __restrict__ lnbL,
            float* __restrict__ miBuf, float* __restrict__ deltaBuf,
            int Nn, int itpg, int njt) {
    __shared__ unsigned short bS[32 * BPITCH];
    __shared__ __align__(16) float aSf[8 * APITCH];
    __shared__ __align__(16) float wdS[KP];
    __shared__ float cjS[32 * 3];
    __shared__ __align__(16) float cbwS[256];
    __shared__ unsigned short mT[4][32 * 36];

    int bid = blockIdx.x;
    int g   = bid / (itpg * njt);
    int r   = bid % (itpg * njt);
    int it  = r / njt;
    int jt  = r % njt;

    int tid  = threadIdx.x;
    int wave = tid >> 6, lane = tid & 63, half = lane >> 5, e = lane & 31;

    int j0  = jt * 32;
    int njr = Nn - j0; if (njr > 32) njr = 32;
    int i0  = it * 8;
    int nir = Nn - i0; if (nir > 8) nir = 8;

    {
        const unsigned int* src = (const unsigned int*)(bH + (size_t)(g * Nn + j0) * KP);
        unsigned int* dst = (unsigned int*)bS;
        int tot = njr * 136;
        for (int x = tid; x < tot; x += 256) {
            int rr = x / 136, c = x % 136;
            dst[rr * (BPITCH / 2) + c] = src[rr * 136 + c];
        }
        const unsigned short* asrc = aH + (size_t)(g * Nn + i0) * KP;
        int at = nir * KP;
        for (int x = tid; x < at; x += 256) {
            int rr = x / KP, k = x % KP;
            aSf[rr * APITCH + k] = bf16_up(asrc[rr * KP + k]);
        }
        for (int x = tid; x < KP; x += 256) wdS[x] = wdFL[x];
        if (tid < njr * 3) cjS[tid] = coorsO[(g * Nn + j0) * 3 + tid];
        if (tid < 256) cbwS[tid] = cbwPL[tid];
    }
    __syncthreads();

    float eb2v = eb2L[e];
    float beta = lnbL[0];
    float cb2v = cb2L[0];

    int  jc     = (e < njr) ? e : (njr - 1);
    bool jvalid = (e < njr);
    float cjx = cjS[jc * 3 + 0], cjy = cjS[jc * 3 + 1], cjz = cjS[jc * 3 + 2];

    unsigned short* mW = &mT[wave][0];
    const unsigned short* bRow = bS + jc * BPITCH;

    int il0 = wave * 2, il1 = wave * 2 + 1;
    bool v0 = il0 < nir, v1 = il1 < nir;
    int gi0 = g * Nn + i0 + (v0 ? il0 : 0);
    int gi1 = g * Nn + i0 + (v1 ? il1 : 0);

    float rx0, ry0, rz0, d0, rx1, ry1, rz1, d1;
    {
        float cx = coorsO[gi0 * 3 + 0], cy = coorsO[gi0 * 3 + 1], cz = coorsO[gi0 * 3 + 2];
        rx0 = cx - cjx; ry0 = cy - cjy; rz0 = cz - cjz;
        d0 = rx0 * rx0 + ry0 * ry0 + rz0 * rz0;
        cx = coorsO[gi1 * 3 + 0]; cy = coorsO[gi1 * 3 + 1]; cz = coorsO[gi1 * 3 + 2];
        rx1 = cx - cjx; ry1 = cy - cjy; rz1 = cz - cjz;
        d1 = rx1 * rx1 + ry1 * ry1 + rz1 * rz1;
    }
    f32x2 d20 = mk2(d0, d0), d21 = mk2(d1, d1);
    const float* aR0 = aSf + (v0 ? il0 : 0) * APITCH;
    const float* aR1 = aSf + (v1 ? il1 : 0) * APITCH;

    f32x16 acc0, acc1;
#pragma unroll
    for (int q = 0; q < 16; q++) { acc0[q] = 0.0f; acc1[q] = 0.0f; }

#pragma unroll
    for (int k0 = 0; k0 < NK0; k0++) {
        int ko = k0 * 16 + half * 8;
        uint2 bA = *(const uint2*)(bRow + ko);
        uint2 bB = *(const uint2*)(bRow + ko + 4);
        f32x4 wv0 = *(const f32x4*)(wdS + ko);
        f32x4 wv1 = *(const f32x4*)(wdS + ko + 4);
        uint4v eu = *(const uint4v*)(ew2PL + ((size_t)k0 * 64 + lane) * 8);
        f32x2 b2_0 = ub2(bA.x), b2_1 = ub2(bA.y), b2_2 = ub2(bB.x), b2_3 = ub2(bB.y);

        f32x4 a00 = *(const f32x4*)(aR0 + ko);
        f32x4 a01 = *(const f32x4*)(aR0 + ko + 4);
        uint4v hu0;
        hu0[0] = hpack(a00.xy, wv0.xy, b2_0, d20);
        hu0[1] = hpack(a00.zw, wv0.zw, b2_1, d20);
        hu0[2] = hpack(a01.xy, wv1.xy, b2_2, d20);
        hu0[3] = hpack(a01.zw, wv1.zw, b2_3, d20);
        acc0 = __builtin_amdgcn_mfma_f32_32x32x16_bf16(
                   __builtin_bit_cast(bf16x8, hu0),
                   __builtin_bit_cast(bf16x8, eu), acc0, 0, 0, 0);

        f32x4 a10 = *(const f32x4*)(aR1 + ko);
        f32x4 a11 = *(const f32x4*)(aR1 + ko + 4);
        uint4v hu1;
        hu1[0] = hpack(a10.xy, wv0.xy, b2_0, d21);
        hu1[1] = hpack(a10.zw, wv0.zw, b2_1, d21);
        hu1[2] = hpack(a11.xy, wv1.xy, b2_2, d21);
        hu1[3] = hpack(a11.zw, wv1.zw, b2_3, d21);
        acc1 = __builtin_amdgcn_mfma_f32_32x32x16_bf16(
                   __builtin_bit_cast(bf16x8, hu1),
                   __builtin_bit_cast(bf16x8, eu), acc1, 0, 0, 0);
    }

    f32x2 ebp = mk2(eb2v, eb2v);

#pragma unroll
    for (int s = 0; s < 2; s++) {
        if (!(s ? v1 : v0)) continue;
        int gi = s ? gi1 : gi0;
        float rx = s ? rx1 : rx0, ry = s ? ry1 : ry0, rz = s ? rz1 : rz0;
        float dist = s ? d1 : d0;

        float mv[16];
        f32x2 mi2 = mk2(0.0f, 0.0f);
        if (njr == 32) {
#pragma unroll
            for (int qp = 0; qp < 8; qp++) {
                int q = qp * 2;
                f32x2 x2 = mk2(s ? acc1[q] : acc0[q], s ? acc1[q + 1] : acc0[q + 1]) + ebp;
                f32x2 m2 = silu2(x2);
                mv[q] = m2.x; mv[q + 1] = m2.y;
                mi2 += m2;
            }
        } else {
#pragma unroll
            for (int qp = 0; qp < 8; qp++) {
                int q = qp * 2;
                f32x2 x2 = mk2(s ? acc1[q] : acc0[q], s ? acc1[q + 1] : acc0[q + 1]) + ebp;
                f32x2 m2 = silu2(x2);
                int row0 = (q & 3) + 8 * (q >> 2) + 4 * half;
                if (j0 + row0 >= Nn) m2.x = 0.0f;
                if (j0 + row0 + 1 >= Nn) m2.y = 0.0f;
                mv[q] = m2.x; mv[q + 1] = m2.y;
                mi2 += m2;
            }
        }
        float miAcc = mi2.x + mi2.y;

#pragma unroll
        for (int q = 0; q < 4; q++) {
            unsigned lo = __builtin_amdgcn_perm(__float_as_uint(mv[q * 4 + 1]),
                                                __float_as_uint(mv[q * 4 + 0]), 0x07060302u);
            unsigned hi = __builtin_amdgcn_perm(__float_as_uint(mv[q * 4 + 3]),
                                                __float_as_uint(mv[q * 4 + 2]), 0x07060302u);
            int row0 = 8 * q + 4 * half;
            *(uint2*)&mW[e * 36 + row0] = make_uint2(lo, hi);
        }

        miAcc += __shfl_xor(miAcc, 32, 64);
        if (half == 0) atomicAdd(&miBuf[gi * MDIM + e], miAcc);

        bf16x8 bq[2];
#pragma unroll
        for (int k0 = 0; k0 < 2; k0++) {
            uint4v t;
#pragma unroll
            for (int p = 0; p < 4; p++) {
                unsigned w0 = mW[(k0 * 16 + half * 8 + 2 * p    ) * 36 + e];
                unsigned w1 = mW[(k0 * 16 + half * 8 + 2 * p + 1) * 36 + e];
                t[p] = w0 | (w1 << 16);
            }
            bq[k0] = __builtin_bit_cast(bf16x8, t);
        }

        f32x2 w2a = mk2(0.0f, 0.0f);
#pragma unroll
        for (int mb = 0; mb < 4; mb++) {
            f32x16 sacc;
#pragma unroll
            for (int q = 0; q < 16; q++) sacc[q] = 0.0f;
#pragma unroll
            for (int k0 = 0; k0 < 2; k0++) {
                uint4v cu = *(const uint4v*)(cw1PL + ((size_t)(mb * 2 + k0) * 64 + lane) * 8);
                sacc = __builtin_amdgcn_mfma_f32_32x32x16_bf16(
                           __builtin_bit_cast(bf16x8, cu), bq[k0], sacc, 0, 0, 0);
            }
            const f32x4* cv = (const f32x4*)(cbwS + (half * 4 + mb) * 32);
#pragma unroll
            for (int qp = 0; qp < 8; qp++) {
                f32x4 c4 = cv[qp];
                f32x2 s2 = mk2(sacc[2 * qp], sacc[2 * qp + 1]) + mk2(c4.x, c4.z);
                f32x2 p2 = silu2(s2);
                w2a = __builtin_elementwise_fma(p2, mk2(c4.y, c4.w), w2a);
            }
        }
        float wAcc = w2a.x + w2a.y;
        wAcc += __shfl_xor(wAcc, 32, 64);
        float w = wAcc + cb2v;
        float nrm = sqrtf(dist);
        float scale = (w * 0.02f) * beta * __builtin_amdgcn_rcpf(fmaxf(nrm, 1e-8f));

        float dAx = 0.0f, dAy = 0.0f, dAz = 0.0f;
        if (jvalid && half == 0) {
            dAx = scale * rx; dAy = scale * ry; dAz = scale * rz;
        }
#pragma unroll
        for (int m = 16; m >= 1; m >>= 1) {
            dAx += __shfl_xor(dAx, m, 64);
            dAy += __shfl_xor(dAy, m, 64);
            dAz += __shfl_xor(dAz, m, 64);
        }
        if (lane == 0) {
            atomicAdd(&deltaBuf[gi * 3 + 0], dAx);
            atomicAdd(&deltaBuf[gi * 3 + 1], dAy);
            atomicAdd(&deltaBuf[gi * 3 + 2], dAz);
        }
    }
}

// ---------------------------------------------------------------------------
__global__ void k_fin(const float* __restrict__ co, const float* __restrict__ dl,
                      float* __restrict__ out) {
    int idx = blockIdx.x * blockDim.x + threadIdx.x;
    if (idx < NNODE * 3) {
        int gnode = idx / 3, c = idx % 3;
        int nf = inv_map(gnode, 1);   // layer 15 is along-l
        out[nf * 3 + c] = co[idx] + dl[idx];
    }
}

// ---------------------------------------------------------------------------
extern "C" void kernel_launch(void* const* d_in, const int* in_sizes, int n_in,
                              void* d_out, int out_size, void* d_ws, size_t ws_size,
                              hipStream_t stream) {
    (void)in_sizes; (void)n_in; (void)out_size; (void)ws_size;

    const int*   tokens  = (const int*)d_in[0];
    const float* cords   = (const float*)d_in[1];
    const float* tok_emb = (const float*)d_in[2];
    const float* pos_emb = (const float*)d_in[3];
    const float* ew1 = (const float*)d_in[4];
    const float* eb1 = (const float*)d_in[5];
    const float* ew2 = (const float*)d_in[6];
    const float* eb2 = (const float*)d_in[7];
    const float* cw1 = (const float*)d_in[8];
    const float* cb1 = (const float*)d_in[9];
    const float* cw2 = (const float*)d_in[10];
    const float* cb2 = (const float*)d_in[11];
    const float* nw1 = (const float*)d_in[12];
    const float* nb1 = (const float*)d_in[13];
    const float* nw2 = (const float*)d_in[14];
    const float* nb2 = (const float*)d_in[15];
    /* d_in[16] = ln_g : multiplied by zeros in the reference -> unused */
    const float* lnb = (const float*)d_in[17];

    float* wf = (float*)d_ws;
    float* featsA = wf; wf += NNODE * DIM;
    float* featsB = wf; wf += NNODE * DIM;
    float* coorsO0 = wf; wf += NNODE * 3;
    float* coorsO1 = wf; wf += NNODE * 3;
    float* mi0  = wf; wf += NNODE * MDIM;
    float* mi1  = wf; wf += NNODE * MDIM;
    float* dl0  = wf; wf += NNODE * 3;
    float* dl1  = wf; wf += NNODE * 3;
    float* cbwP = wf; wf += NLAY * 256;
    float* wdF  = wf; wf += NLAY * KP;

    uintptr_t p = (uintptr_t)wf; p = (p + 15) & ~(uintptr_t)15;
    unsigned short* wh = (unsigned short*)p;
    unsigned short* aHb  = wh; wh += (size_t)NNODE * KP;
    unsigned short* bHb  = wh; wh += (size_t)NNODE * KP;
    unsigned short* ew2P = wh; wh += NLAY * NK0 * 512;
    unsigned short* cw1P = wh; wh += NLAY * 4096;
    unsigned short* ew1P = wh; wh += (size_t)NLAY * NT2 * 4 * 512;
    unsigned short* nw1P = wh; wh += (size_t)NLAY * 4 * 6 * 512;
    unsigned short* nw2P = wh; wh += (size_t)NLAY * 2 * 8 * 512;

    float* coorsO[2] = {coorsO0, coorsO1};
    float* miB[2]    = {mi0, mi1};
    float* dlB[2]    = {dl0, dl1};

    int prepN = NLAY * NT2 * 4 * 512;
    k_prep<<<(prepN + 255) / 256, 256, 0, stream>>>(
        ew1, ew2, cw1, cb1, cw2, nw1, nw2,
        wdF, ew2P, cw1P, cbwP, ew1P, nw1P, nw2P);
    k_embed<<<(NNODE * DIM + 255) / 256, 256, 0, stream>>>(
        tokens, tok_emb, pos_emb, featsA);

    float* fCur = featsA; float* fNxt = featsB;

    k_np<<<(NNODE / 32) * 4, 256, 0, stream>>>(
        fCur, cords, nullptr, nullptr,
        nullptr, nullptr, nullptr, nullptr,
        ew1P + 0, eb1 + 0,
        fNxt, coorsO[0], miB[0], dlB[0],
        aHb, bHb, 0, 0, 0);

    for (int L = 0; L < NLAY; L++) {
        int alongL = (L / 4) % 2;
        int idx  = L & 1;
        int Nn   = alongL ? LL : NN;
        int njt  = alongL ? 3 : 1;
        int itpg = (Nn + 7) / 8;
        int groups = NNODE / Nn;

        k_edge<<<groups * itpg * njt, 256, 0, stream>>>(
            aHb, bHb, coorsO[idx],
            wdF + L * KP, ew2P + (size_t)L * NK0 * 512, eb2 + L * MDIM,
            cw1P + (size_t)L * 4096, cbwP + (size_t)L * 256,
            cb2 + L, lnb + L, miB[idx], dlB[idx], Nn, itpg, njt);

        if (L < NLAY - 1) {
            int aL1 = ((L + 1) / 4) % 2;
            int nidx = (L + 1) & 1;
            k_np<<<(NNODE / 32) * 4, 256, 0, stream>>>(
                fCur, coorsO[idx], miB[idx], dlB[idx],
                nw1P + (size_t)L * 4 * 6 * 512, nb1 + L * NH,
                nw2P + (size_t)L * 2 * 8 * 512, nb2 + L * DIM,
                ew1P + (size_t)(L + 1) * NT2 * 4 * 512, eb1 + (size_t)(L + 1) * EH,
                fNxt, coorsO[nidx], miB[nidx], dlB[nidx],
                aHb, bHb, alongL, aL1, 1);
            float* t = fCur; fCur = fNxt; fNxt = t;
        } else {
            k_fin<<<(NNODE * 3 + 255) / 256, 256, 0, stream>>>(
                coorsO[idx], dlB[idx], (float*)d_out);
        }
    }
}

// Round 11
// 930.308 us; speedup vs baseline: 1.1609x; 1.0019x over previous
//
#include <hip/hip_runtime.h>
#include <math.h>

#define DIM   64
#define MDIM  32
#define NLAY  16
#define PAD   1
#define NB    2
#define LL    96
#define NN    23
#define NNODE (NB*LL*NN)   /* 4416 */
#define EIN   129
#define EH    258          /* EIN*2 */
#define KP    272          /* EH padded to 17*16 */
#define NK0   17
#define NH    128          /* DIM*2 */
#define BPITCH 276         /* bS pitch shorts */
#define APITCH 276         /* aS pitch floats (16B rows) */
#define NT2   18           /* a: 9 tiles (288), b: 9 tiles (288) */
#define XP    104
#define HP    136
#define OPS   168          /* outS pitch shorts in split k_np */

typedef __attribute__((ext_vector_type(8)))  short        bf16x8;
typedef __attribute__((ext_vector_type(16))) float        f32x16;
typedef __attribute__((ext_vector_type(4)))  unsigned int uint4v;
typedef __attribute__((ext_vector_type(2)))  float        f32x2;
typedef __attribute__((ext_vector_type(4)))  float        f32x4;

__device__ __forceinline__ f32x2 mk2(float a, float b) { f32x2 r; r.x = a; r.y = b; return r; }

__device__ __forceinline__ float silu_f(float x) {
    float e = __expf(-x);
    return x * __builtin_amdgcn_rcpf(1.0f + e);
}
// packed silu: independent rcp per pair (shallow dependency chain — R6 winner)
__device__ __forceinline__ f32x2 silu2(f32x2 x) {
    f32x2 t = x * (-1.44269504f);
    f32x2 e;
    e.x = __builtin_amdgcn_exp2f(t.x);
    e.y = __builtin_amdgcn_exp2f(t.y);
    f32x2 den = e + 1.0f;
    f32x2 r;
    r.x = __builtin_amdgcn_rcpf(den.x);
    r.y = __builtin_amdgcn_rcpf(den.y);
    return x * r;
}
__device__ __forceinline__ unsigned short bf16_rn(float x) {
    unsigned u = __float_as_uint(x);
    u += 0x7FFF + ((u >> 16) & 1);
    return (unsigned short)(u >> 16);
}
__device__ __forceinline__ float bf16_up(unsigned short h) {
    return __uint_as_float(((unsigned)h) << 16);
}
__device__ __forceinline__ f32x2 ub2(unsigned bw) {
    return mk2(__uint_as_float(bw << 16), __uint_as_float(bw & 0xFFFF0000u));
}
__device__ __forceinline__ unsigned hpack(f32x2 a2, f32x2 w2, f32x2 b2, f32x2 d2) {
    f32x2 x2 = a2 + b2;
    x2 = __builtin_elementwise_fma(d2, w2, x2);
    f32x2 h2 = silu2(x2);
    return __builtin_amdgcn_perm(__float_as_uint(h2.y), __float_as_uint(h2.x), 0x07060302u);
}
__device__ __forceinline__ int fwd_map(int nf, int alongL) {
    if (alongL) {
        int b = nf / (LL * NN);
        int rem = nf % (LL * NN);
        int l = rem / NN, n = rem % NN;
        return (b * NN + n) * LL + l;
    }
    return nf;
}
__device__ __forceinline__ int inv_map(int gnode, int alongL) {
    if (alongL) {
        int g = gnode / LL, l = gnode % LL;
        int b = g / NN, n = g % NN;
        return (b * LL + l) * NN + n;
    }
    return gnode;
}

// ---------------------------------------------------------------------------
__global__ void k_embed(const int* __restrict__ tokens,
                        const float* __restrict__ tok_emb,
                        const float* __restrict__ pos_emb,
                        float* __restrict__ feats) {
    int idx = blockIdx.x * blockDim.x + threadIdx.x;
    if (idx < NNODE * DIM) {
        int node = idx / DIM, d = idx % DIM;
        int b = node / (LL * NN);
        int rem = node % (LL * NN);
        int n = rem % NN;
        int l = rem / NN;
        int t = tokens[b * LL + l];
        float f = tok_emb[t * DIM + d];
        if (t != PAD) f += pos_emb[(n + 2) * DIM + d];
        feats[idx] = f;
    }
}

// ---------------------------------------------------------------------------
__global__ void k_prep(const float* __restrict__ ew1, const float* __restrict__ ew2,
                       const float* __restrict__ cw1, const float* __restrict__ cb1,
                       const float* __restrict__ cw2,
                       const float* __restrict__ nw1, const float* __restrict__ nw2,
                       float* __restrict__ wdF, unsigned short* __restrict__ ew2P,
                       unsigned short* __restrict__ cw1P,
                       float* __restrict__ cbwP,
                       unsigned short* __restrict__ ew1P,
                       unsigned short* __restrict__ nw1P,
                       unsigned short* __restrict__ nw2P) {
    int idx = blockIdx.x * blockDim.x + threadIdx.x;
    if (idx < NLAY * KP) {
        int L = idx / KP, k = idx % KP;
        float v = (k < EH) ? ew1[(size_t)L * EIN * EH + 128 * EH + k] : 0.0f;
        wdF[idx] = bf16_up(bf16_rn(v));
    }
    if (idx < NLAY * NK0 * 512) {
        int L = idx / (NK0 * 512); int r = idx % (NK0 * 512);
        int k0 = r / 512; int r2 = r % 512;
        int lane = r2 >> 3, j = r2 & 7;
        int k = k0 * 16 + (lane >> 5) * 8 + j;
        int n = lane & 31;
        float v = (k < EH) ? ew2[((size_t)L * EH + k) * MDIM + n] : 0.0f;
        ew2P[idx] = bf16_rn(v);
    }
    if (idx < NLAY * 4096) {
        int L = idx / 4096; int r = idx % 4096;
        int mb = r / 1024; int r2 = r % 1024;
        int k0 = r2 / 512; int r3 = r2 % 512;
        int lane = r3 >> 3, j = r3 & 7;
        int k = k0 * 16 + (lane >> 5) * 8 + j;
        int o = mb * 32 + (lane & 31);
        cw1P[idx] = bf16_rn(cw1[((size_t)L * MDIM + k) * NH + o]);
    }
    if (idx < NLAY * 128) {
        int L = idx / 128; int r = idx % 128;
        int hlf = r / 64; int r2 = r % 64;
        int mb = r2 / 16, reg = r2 % 16;
        int o = mb * 32 + (reg & 3) + 8 * (reg >> 2) + 4 * hlf;
        cbwP[(size_t)L * 256 + r * 2 + 0] = cb1[L * NH + o];
        cbwP[(size_t)L * 256 + r * 2 + 1] = cw2[L * NH + o];
    }
    // ew1P: NT2=18 tiles; tiles 0-8 = a (c 0..287, real <258), 9-17 = b
    if (idx < NLAY * NT2 * 4 * 512) {
        int L = idx / (NT2 * 4 * 512); int r = idx % (NT2 * 4 * 512);
        int nt = r / 2048; int r2 = r % 2048;
        int ks = r2 / 512; int r3 = r2 % 512;
        int lane = r3 >> 3, j = r3 & 7;
        int d = ks * 16 + (lane >> 5) * 8 + j;
        int c = nt * 32 + (lane & 31);              // 0..575
        float v = 0.0f;
        if (c < 288) { if (c < EH) v = ew1[(size_t)L * EIN * EH + d * EH + c]; }
        else { int ob = c - 288; if (ob < EH) v = ew1[(size_t)L * EIN * EH + (DIM + d) * EH + ob]; }
        ew1P[idx] = bf16_rn(v);
    }
    if (idx < NLAY * 4 * 6 * 512) {
        int L = idx / 12288; int r = idx % 12288;
        int nt = r / 3072; int r2 = r % 3072;
        int ks = r2 / 512; int r3 = r2 % 512;
        int lane = r3 >> 3, j = r3 & 7;
        int k = ks * 16 + (lane >> 5) * 8 + j;
        int n = nt * 32 + (lane & 31);
        nw1P[idx] = bf16_rn(nw1[((size_t)L * (DIM + MDIM) + k) * NH + n]);
    }
    if (idx < NLAY * 2 * 8 * 512) {
        int L = idx / 8192; int r = idx % 8192;
        int nt = r / 4096; int r2 = r % 4096;
        int ks = r2 / 512; int r3 = r2 % 512;
        int lane = r3 >> 3, j = r3 & 7;
        int k = ks * 16 + (lane >> 5) * 8 + j;
        int n = nt * 32 + (lane & 31);
        nw2P[idx] = bf16_rn(nw2[((size_t)L * NH + k) * DIM + n]);
    }
}

// ---------------------------------------------------------------------------
// Fused node-MLP(L) + pre(L+1), 4-way N-split: grid = (NNODE/32)*4.
// ---------------------------------------------------------------------------
__global__ __launch_bounds__(256)
void k_np(const float* __restrict__ fIn, const float* __restrict__ coSrc,
          const float* __restrict__ miL, const float* __restrict__ dL,
          const unsigned short* __restrict__ nw1PL, const float* __restrict__ nb1L,
          const unsigned short* __restrict__ nw2PL, const float* __restrict__ nb2L,
          const unsigned short* __restrict__ ew1PL, const float* __restrict__ eb1L,
          float* __restrict__ fOut, float* __restrict__ coDst,
          float* __restrict__ miNext, float* __restrict__ dNext,
          unsigned short* __restrict__ aH, unsigned short* __restrict__ bH,
          int aL0, int aL1, int doNode) {
    __shared__ unsigned short xS[32 * XP];
    __shared__ unsigned short hS[32 * HP];
    __shared__ unsigned short outS[32 * OPS];
    __shared__ int gsrcS[32], gdstS[32];

    int bid  = blockIdx.x;
    int tileB = bid >> 2, par = bid & 3;
    int n0  = tileB * 32;
    int tid = threadIdx.x;
    int wave = tid >> 6, lane = tid & 63, half = lane >> 5, e = lane & 31;

    if (tid < 32) {
        gsrcS[tid] = fwd_map(n0 + tid, aL0);
        gdstS[tid] = fwd_map(n0 + tid, aL1);
    }
    __syncthreads();

    for (int i = 0; i < 8; i++) {
        int x = tid + 256 * i;
        int node = x >> 6, d = x & 63;
        xS[node * XP + d] = bf16_rn(fIn[(n0 + node) * DIM + d]);
    }
    if (doNode) {
        for (int i = 0; i < 4; i++) {
            int x = tid + 256 * i;
            int node = x >> 5, d = x & 31;
            xS[node * XP + DIM + d] = bf16_rn(miL[(size_t)gsrcS[node] * MDIM + d]);
        }
    }
    if (par == 0) {
        if (tid < 96) {
            int node = tid / 3, c = tid % 3;
            int gs = gsrcS[node], gd = gdstS[node];
            float cv = coSrc[gs * 3 + c] + (doNode ? dL[gs * 3 + c] : 0.0f);
            coDst[gd * 3 + c] = cv;
            dNext[gd * 3 + c] = 0.0f;
        }
        for (int i = 0; i < 4; i++) {
            int x = tid + 256 * i;
            int node = x >> 5, d = x & 31;
            miNext[(size_t)gdstS[node] * MDIM + d] = 0.0f;
        }
    }
    __syncthreads();

    if (doNode) {
        {
            int nt = wave;
            f32x16 acc;
#pragma unroll
            for (int q = 0; q < 16; q++) acc[q] = 0.0f;
#pragma unroll
            for (int ks = 0; ks < 6; ks++) {
                uint4v au = *(const uint4v*)(xS + e * XP + ks * 16 + half * 8);
                uint4v bu = *(const uint4v*)(nw1PL + ((size_t)(nt * 6 + ks) * 512 + lane * 8));
                acc = __builtin_amdgcn_mfma_f32_32x32x16_bf16(
                          __builtin_bit_cast(bf16x8, au),
                          __builtin_bit_cast(bf16x8, bu), acc, 0, 0, 0);
            }
            int o = nt * 32 + e;
            float b1 = nb1L[o];
#pragma unroll
            for (int q = 0; q < 16; q++) {
                int row = (q & 3) + 8 * (q >> 2) + 4 * half;
                hS[row * HP + o] = bf16_rn(silu_f(acc[q] + b1));
            }
        }
        __syncthreads();

        if (wave < 2) {
            int nt = wave;
            f32x16 acc;
#pragma unroll
            for (int q = 0; q < 16; q++) acc[q] = 0.0f;
#pragma unroll
            for (int ks = 0; ks < 8; ks++) {
                uint4v au = *(const uint4v*)(hS + e * HP + ks * 16 + half * 8);
                uint4v bu = *(const uint4v*)(nw2PL + ((size_t)(nt * 8 + ks) * 512 + lane * 8));
                acc = __builtin_amdgcn_mfma_f32_32x32x16_bf16(
                          __builtin_bit_cast(bf16x8, au),
                          __builtin_bit_cast(bf16x8, bu), acc, 0, 0, 0);
            }
            int o = nt * 32 + e;
            float b2 = nb2L[o];
#pragma unroll
            for (int q = 0; q < 16; q++) {
                int row = (q & 3) + 8 * (q >> 2) + 4 * half;
                float fo = acc[q] + b2 + bf16_up(xS[row * XP + o]);
                if (par == 0) fOut[(size_t)(n0 + row) * DIM + o] = fo;
                xS[row * XP + o] = bf16_rn(fo);
            }
        }
        __syncthreads();
    }

    // ---- GEMM3: this block's tiles nt = par + lt*4 ----
    {
        uint4v afrag[4];
#pragma unroll
        for (int ks = 0; ks < 4; ks++)
            afrag[ks] = *(const uint4v*)(xS + e * XP + ks * 16 + half * 8);

        for (int lt = wave; lt < 5; lt += 4) {
            int nt = par + lt * 4;
            if (nt >= NT2) continue;
            f32x16 acc;
#pragma unroll
            for (int q = 0; q < 16; q++) acc[q] = 0.0f;
#pragma unroll
            for (int ks = 0; ks < 4; ks++) {
                uint4v bu = *(const uint4v*)(ew1PL + ((size_t)(nt * 4 + ks) * 512 + lane * 8));
                acc = __builtin_amdgcn_mfma_f32_32x32x16_bf16(
                          __builtin_bit_cast(bf16x8, afrag[ks]),
                          __builtin_bit_cast(bf16x8, bu), acc, 0, 0, 0);
            }
            int c = nt * 32 + e;
            bool isA = c < 288;
            int oc = isA ? c : (c - 288);
            bool valid = oc < EH;
            float eb = (isA && valid) ? eb1L[oc] : 0.0f;
#pragma unroll
            for (int q = 0; q < 16; q++) {
                int row = (q & 3) + 8 * (q >> 2) + 4 * half;
                float v = valid ? (acc[q] + eb) : 0.0f;
                outS[row * OPS + lt * 32 + e] = bf16_rn(v);
            }
        }
    }
    __syncthreads();

    // ---- coalesced writeback of owned 16B chunks ----
    {
        int nch = (par < 2) ? 20 : 16;
        for (int x = tid; x < 32 * nch; x += 256) {
            int row = x / nch, cl = x % nch;
            int lt = cl >> 2, sub = cl & 3;
            int nt = par + lt * 4;
            uint4v v = *(const uint4v*)(outS + row * OPS + lt * 32 + sub * 8);
            int gd = gdstS[row];
            if (nt < 9) {
                int col = nt * 32 + sub * 8;
                if (col < KP) *(uint4v*)(aH + (size_t)gd * KP + col) = v;
            } else {
                int col = (nt - 9) * 32 + sub * 8;
                if (col < KP) *(uint4v*)(bH + (size_t)gd * KP + col) = v;
            }
        }
    }
}

// ---------------------------------------------------------------------------
// MFMA edge kernel — R6 structure, launch_bounds bumped to 4 blocks/CU
// (VGPR 64 ≤ 128 cap, LDS 38.4 KB ≤ 40 KB → 4 blocks fit).
// ---------------------------------------------------------------------------
__global__ __launch_bounds__(256, 4)
void k_edge(const unsigned short* __restrict__ aH,
            const unsigned short* __restrict__ bH,
            const float* __restrict__ coorsO,
            const float* __restrict__ wdFL,
            const unsigned short* __restrict__ ew2PL,
            const float* __restrict__ eb2L,
            const unsigned short* __restrict__ cw1PL,
            const float* __restrict__ cbwPL,
            const float* __restrict__ cb2L,
            const float* __restrict__ lnbL,
            float* __restrict__ miBuf, float* __restrict__ deltaBuf,
            int Nn, int itpg, int njt) {
    __shared__ unsigned short bS[32 * BPITCH];
    __shared__ __align__(16) float aSf[8 * APITCH];
    __shared__ __align__(16) float wdS[KP];
    __shared__ float cjS[32 * 3];
    __shared__ __align__(16) float cbwS[256];
    __shared__ unsigned short mT[4][32 * 36];

    int bid = blockIdx.x;
    int g   = bid / (itpg * njt);
    int r   = bid % (itpg * njt);
    int it  = r / njt;
    int jt  = r % njt;

    int tid  = threadIdx.x;
    int wave = tid >> 6, lane = tid & 63, half = lane >> 5, e = lane & 31;

    int j0  = jt * 32;
    int njr = Nn - j0; if (njr > 32) njr = 32;
    int i0  = it * 8;
    int nir = Nn - i0; if (nir > 8) nir = 8;

    {
        const unsigned int* src = (const unsigned int*)(bH + (size_t)(g * Nn + j0) * KP);
        unsigned int* dst = (unsigned int*)bS;
        int tot = njr * 136;
        for (int x = tid; x < tot; x += 256) {
            int rr = x / 136, c = x % 136;
            dst[rr * (BPITCH / 2) + c] = src[rr * 136 + c];
        }
        const unsigned short* asrc = aH + (size_t)(g * Nn + i0) * KP;
        int at = nir * KP;
        for (int x = tid; x < at; x += 256) {
            int rr = x / KP, k = x % KP;
            aSf[rr * APITCH + k] = bf16_up(asrc[rr * KP + k]);
        }
        for (int x = tid; x < KP; x += 256) wdS[x] = wdFL[x];
        if (tid < njr * 3) cjS[tid] = coorsO[(g * Nn + j0) * 3 + tid];
        if (tid < 256) cbwS[tid] = cbwPL[tid];
    }
    __syncthreads();

    float eb2v = eb2L[e];
    float beta = lnbL[0];
    float cb2v = cb2L[0];

    int  jc     = (e < njr) ? e : (njr - 1);
    bool jvalid = (e < njr);
    float cjx = cjS[jc * 3 + 0], cjy = cjS[jc * 3 + 1], cjz = cjS[jc * 3 + 2];

    unsigned short* mW = &mT[wave][0];
    const unsigned short* bRow = bS + jc * BPITCH;

    int il0 = wave * 2, il1 = wave * 2 + 1;
    bool v0 = il0 < nir, v1 = il1 < nir;
    int gi0 = g * Nn + i0 + (v0 ? il0 : 0);
    int gi1 = g * Nn + i0 + (v1 ? il1 : 0);

    float rx0, ry0, rz0, d0, rx1, ry1, rz1, d1;
    {
        float cx = coorsO[gi0 * 3 + 0], cy = coorsO[gi0 * 3 + 1], cz = coorsO[gi0 * 3 + 2];
        rx0 = cx - cjx; ry0 = cy - cjy; rz0 = cz - cjz;
        d0 = rx0 * rx0 + ry0 * ry0 + rz0 * rz0;
        cx = coorsO[gi1 * 3 + 0]; cy = coorsO[gi1 * 3 + 1]; cz = coorsO[gi1 * 3 + 2];
        rx1 = cx - cjx; ry1 = cy - cjy; rz1 = cz - cjz;
        d1 = rx1 * rx1 + ry1 * ry1 + rz1 * rz1;
    }
    f32x2 d20 = mk2(d0, d0), d21 = mk2(d1, d1);
    const float* aR0 = aSf + (v0 ? il0 : 0) * APITCH;
    const float* aR1 = aSf + (v1 ? il1 : 0) * APITCH;

    f32x16 acc0, acc1;
#pragma unroll
    for (int q = 0; q < 16; q++) { acc0[q] = 0.0f; acc1[q] = 0.0f; }

#pragma unroll
    for (int k0 = 0; k0 < NK0; k0++) {
        int ko = k0 * 16 + half * 8;
        uint2 bA = *(const uint2*)(bRow + ko);
        uint2 bB = *(const uint2*)(bRow + ko + 4);
        f32x4 wv0 = *(const f32x4*)(wdS + ko);
        f32x4 wv1 = *(const f32x4*)(wdS + ko + 4);
        uint4v eu = *(const uint4v*)(ew2PL + ((size_t)k0 * 64 + lane) * 8);
        f32x2 b2_0 = ub2(bA.x), b2_1 = ub2(bA.y), b2_2 = ub2(bB.x), b2_3 = ub2(bB.y);

        f32x4 a00 = *(const f32x4*)(aR0 + ko);
        f32x4 a01 = *(const f32x4*)(aR0 + ko + 4);
        uint4v hu0;
        hu0[0] = hpack(a00.xy, wv0.xy, b2_0, d20);
        hu0[1] = hpack(a00.zw, wv0.zw, b2_1, d20);
        hu0[2] = hpack(a01.xy, wv1.xy, b2_2, d20);
        hu0[3] = hpack(a01.zw, wv1.zw, b2_3, d20);
        acc0 = __builtin_amdgcn_mfma_f32_32x32x16_bf16(
                   __builtin_bit_cast(bf16x8, hu0),
                   __builtin_bit_cast(bf16x8, eu), acc0, 0, 0, 0);

        f32x4 a10 = *(const f32x4*)(aR1 + ko);
        f32x4 a11 = *(const f32x4*)(aR1 + ko + 4);
        uint4v hu1;
        hu1[0] = hpack(a10.xy, wv0.xy, b2_0, d21);
        hu1[1] = hpack(a10.zw, wv0.zw, b2_1, d21);
        hu1[2] = hpack(a11.xy, wv1.xy, b2_2, d21);
        hu1[3] = hpack(a11.zw, wv1.zw, b2_3, d21);
        acc1 = __builtin_amdgcn_mfma_f32_32x32x16_bf16(
                   __builtin_bit_cast(bf16x8, hu1),
                   __builtin_bit_cast(bf16x8, eu), acc1, 0, 0, 0);
    }

    f32x2 ebp = mk2(eb2v, eb2v);

#pragma unroll
    for (int s = 0; s < 2; s++) {
        if (!(s ? v1 : v0)) continue;
        int gi = s ? gi1 : gi0;
        float rx = s ? rx1 : rx0, ry = s ? ry1 : ry0, rz = s ? rz1 : rz0;
        float dist = s ? d1 : d0;

        float mv[16];
        f32x2 mi2 = mk2(0.0f, 0.0f);
        if (njr == 32) {
#pragma unroll
            for (int qp = 0; qp < 8; qp++) {
                int q = qp * 2;
                f32x2 x2 = mk2(s ? acc1[q] : acc0[q], s ? acc1[q + 1] : acc0[q + 1]) + ebp;
                f32x2 m2 = silu2(x2);
                mv[q] = m2.x; mv[q + 1] = m2.y;
                mi2 += m2;
            }
        } else {
#pragma unroll
            for (int qp = 0; qp < 8; qp++) {
                int q = qp * 2;
                f32x2 x2 = mk2(s ? acc1[q] : acc0[q], s ? acc1[q + 1] : acc0[q + 1]) + ebp;
                f32x2 m2 = silu2(x2);
                int row0 = (q & 3) + 8 * (q >> 2) + 4 * half;
                if (j0 + row0 >= Nn) m2.x = 0.0f;
                if (j0 + row0 + 1 >= Nn) m2.y = 0.0f;
                mv[q] = m2.x; mv[q + 1] = m2.y;
                mi2 += m2;
            }
        }
        float miAcc = mi2.x + mi2.y;

#pragma unroll
        for (int q = 0; q < 4; q++) {
            unsigned lo = __builtin_amdgcn_perm(__float_as_uint(mv[q * 4 + 1]),
                                                __float_as_uint(mv[q * 4 + 0]), 0x07060302u);
            unsigned hi = __builtin_amdgcn_perm(__float_as_uint(mv[q * 4 + 3]),
                                                __float_as_uint(mv[q * 4 + 2]), 0x07060302u);
            int row0 = 8 * q + 4 * half;
            *(uint2*)&mW[e * 36 + row0] = make_uint2(lo, hi);
        }

        miAcc += __shfl_xor(miAcc, 32, 64);
        if (half == 0) atomicAdd(&miBuf[gi * MDIM + e], miAcc);

        bf16x8 bq[2];
#pragma unroll
        for (int k0 = 0; k0 < 2; k0++) {
            uint4v t;
#pragma unroll
            for (int p = 0; p < 4; p++) {
                unsigned w0 = mW[(k0 * 16 + half * 8 + 2 * p    ) * 36 + e];
                unsigned w1 = mW[(k0 * 16 + half * 8 + 2 * p + 1) * 36 + e];
                t[p] = w0 | (w1 << 16);
            }
            bq[k0] = __builtin_bit_cast(bf16x8, t);
        }

        f32x2 w2a = mk2(0.0f, 0.0f);
#pragma unroll
        for (int mb = 0; mb < 4; mb++) {
            f32x16 sacc;
#pragma unroll
            for (int q = 0; q < 16; q++) sacc[q] = 0.0f;
#pragma unroll
            for (int k0 = 0; k0 < 2; k0++) {
                uint4v cu = *(const uint4v*)(cw1PL + ((size_t)(mb * 2 + k0) * 64 + lane) * 8);
                sacc = __builtin_amdgcn_mfma_f32_32x32x16_bf16(
                           __builtin_bit_cast(bf16x8, cu), bq[k0], sacc, 0, 0, 0);
            }
            const f32x4* cv = (const f32x4*)(cbwS + (half * 4 + mb) * 32);
#pragma unroll
            for (int qp = 0; qp < 8; qp++) {
                f32x4 c4 = cv[qp];
                f32x2 s2 = mk2(sacc[2 * qp], sacc[2 * qp + 1]) + mk2(c4.x, c4.z);
                f32x2 p2 = silu2(s2);
                w2a = __builtin_elementwise_fma(p2, mk2(c4.y, c4.w), w2a);
            }
        }
        float wAcc = w2a.x + w2a.y;
        wAcc += __shfl_xor(wAcc, 32, 64);
        float w = wAcc + cb2v;
        float nrm = sqrtf(dist);
        float scale = (w * 0.02f) * beta * __builtin_amdgcn_rcpf(fmaxf(nrm, 1e-8f));

        float dAx = 0.0f, dAy = 0.0f, dAz = 0.0f;
        if (jvalid && half == 0) {
            dAx = scale * rx; dAy = scale * ry; dAz = scale * rz;
        }
#pragma unroll
        for (int m = 16; m >= 1; m >>= 1) {
            dAx += __shfl_xor(dAx, m, 64);
            dAy += __shfl_xor(dAy, m, 64);
            dAz += __shfl_xor(dAz, m, 64);
        }
        if (lane == 0) {
            atomicAdd(&deltaBuf[gi * 3 + 0], dAx);
            atomicAdd(&deltaBuf[gi * 3 + 1], dAy);
            atomicAdd(&deltaBuf[gi * 3 + 2], dAz);
        }
    }
}

// ---------------------------------------------------------------------------
__global__ void k_fin(const float* __restrict__ co, const float* __restrict__ dl,
                      float* __restrict__ out) {
    int idx = blockIdx.x * blockDim.x + threadIdx.x;
    if (idx < NNODE * 3) {
        int gnode = idx / 3, c = idx % 3;
        int nf = inv_map(gnode, 1);   // layer 15 is along-l
        out[nf * 3 + c] = co[idx] + dl[idx];
    }
}

// ---------------------------------------------------------------------------
extern "C" void kernel_launch(void* const* d_in, const int* in_sizes, int n_in,
                              void* d_out, int out_size, void* d_ws, size_t ws_size,
                              hipStream_t stream) {
    (void)in_sizes; (void)n_in; (void)out_size; (void)ws_size;

    const int*   tokens  = (const int*)d_in[0];
    const float* cords   = (const float*)d_in[1];
    const float* tok_emb = (const float*)d_in[2];
    const float* pos_emb = (const float*)d_in[3];
    const float* ew1 = (const float*)d_in[4];
    const float* eb1 = (const float*)d_in[5];
    const float* ew2 = (const float*)d_in[6];
    const float* eb2 = (const float*)d_in[7];
    const float* cw1 = (const float*)d_in[8];
    const float* cb1 = (const float*)d_in[9];
    const float* cw2 = (const float*)d_in[10];
    const float* cb2 = (const float*)d_in[11];
    const float* nw1 = (const float*)d_in[12];
    const float* nb1 = (const float*)d_in[13];
    const float* nw2 = (const float*)d_in[14];
    const float* nb2 = (const float*)d_in[15];
    /* d_in[16] = ln_g : multiplied by zeros in the reference -> unused */
    const float* lnb = (const float*)d_in[17];

    float* wf = (float*)d_ws;
    float* featsA = wf; wf += NNODE * DIM;
    float* featsB = wf; wf += NNODE * DIM;
    float* coorsO0 = wf; wf += NNODE * 3;
    float* coorsO1 = wf; wf += NNODE * 3;
    float* mi0  = wf; wf += NNODE * MDIM;
    float* mi1  = wf; wf += NNODE * MDIM;
    float* dl0  = wf; wf += NNODE * 3;
    float* dl1  = wf; wf += NNODE * 3;
    float* cbwP = wf; wf += NLAY * 256;
    float* wdF  = wf; wf += NLAY * KP;

    uintptr_t p = (uintptr_t)wf; p = (p + 15) & ~(uintptr_t)15;
    unsigned short* wh = (unsigned short*)p;
    unsigned short* aHb  = wh; wh += (size_t)NNODE * KP;
    unsigned short* bHb  = wh; wh += (size_t)NNODE * KP;
    unsigned short* ew2P = wh; wh += NLAY * NK0 * 512;
    unsigned short* cw1P = wh; wh += NLAY * 4096;
    unsigned short* ew1P = wh; wh += (size_t)NLAY * NT2 * 4 * 512;
    unsigned short* nw1P = wh; wh += (size_t)NLAY * 4 * 6 * 512;
    unsigned short* nw2P = wh; wh += (size_t)NLAY * 2 * 8 * 512;

    float* coorsO[2] = {coorsO0, coorsO1};
    float* miB[2]    = {mi0, mi1};
    float* dlB[2]    = {dl0, dl1};

    int prepN = NLAY * NT2 * 4 * 512;
    k_prep<<<(prepN + 255) / 256, 256, 0, stream>>>(
        ew1, ew2, cw1, cb1, cw2, nw1, nw2,
        wdF, ew2P, cw1P, cbwP, ew1P, nw1P, nw2P);
    k_embed<<<(NNODE * DIM + 255) / 256, 256, 0, stream>>>(
        tokens, tok_emb, pos_emb, featsA);

    float* fCur = featsA; float* fNxt = featsB;

    k_np<<<(NNODE / 32) * 4, 256, 0, stream>>>(
        fCur, cords, nullptr, nullptr,
        nullptr, nullptr, nullptr, nullptr,
        ew1P + 0, eb1 + 0,
        fNxt, coorsO[0], miB[0], dlB[0],
        aHb, bHb, 0, 0, 0);

    for (int L = 0; L < NLAY; L++) {
        int alongL = (L / 4) % 2;
        int idx  = L & 1;
        int Nn   = alongL ? LL : NN;
        int njt  = alongL ? 3 : 1;
        int itpg = (Nn + 7) / 8;
        int groups = NNODE / Nn;

        k_edge<<<groups * itpg * njt, 256, 0, stream>>>(
            aHb, bHb, coorsO[idx],
            wdF + L * KP, ew2P + (size_t)L * NK0 * 512, eb2 + L * MDIM,
            cw1P + (size_t)L * 4096, cbwP + (size_t)L * 256,
            cb2 + L, lnb + L, miB[idx], dlB[idx], Nn, itpg, njt);

        if (L < NLAY - 1) {
            int aL1 = ((L + 1) / 4) % 2;
            int nidx = (L + 1) & 1;
            k_np<<<(NNODE / 32) * 4, 256, 0, stream>>>(
                fCur, coorsO[idx], miB[idx], dlB[idx],
                nw1P + (size_t)L * 4 * 6 * 512, nb1 + L * NH,
                nw2P + (size_t)L * 2 * 8 * 512, nb2 + L * DIM,
                ew1P + (size_t)(L + 1) * NT2 * 4 * 512, eb1 + (size_t)(L + 1) * EH,
                fNxt, coorsO[nidx], miB[nidx], dlB[nidx],
                aHb, bHb, alongL, aL1, 1);
            float* t = fCur; fCur = fNxt; fNxt = t;
        } else {
            k_fin<<<(NNODE * 3 + 255) / 256, 256, 0, stream>>>(
                coorsO[idx], dlB[idx], (float*)d_out);
        }
    }
}

// Round 12
// 886.399 us; speedup vs baseline: 1.2185x; 1.0495x over previous
//
#include <hip/hip_runtime.h>
#include <math.h>

#define DIM   64
#define MDIM  32
#define NLAY  16
#define PAD   1
#define NB    2
#define LL    96
#define NN    23
#define NNODE (NB*LL*NN)   /* 4416 */
#define EIN   129
#define EH    258          /* EIN*2 */
#define KP    272          /* EH padded to 17*16 */
#define NK0   17
#define NH    128          /* DIM*2 */
#define BPITCH 276         /* bS pitch shorts */
#define APITCH 276         /* aS pitch floats (16B rows) */
#define NT2   18           /* a: 9 tiles (288), b: 9 tiles (288) */
#define XP    104
#define HP    136
#define OPS   168          /* outS pitch shorts in split k_np */

typedef __attribute__((ext_vector_type(8)))  short        bf16x8;
typedef __attribute__((ext_vector_type(16))) float        f32x16;
typedef __attribute__((ext_vector_type(4)))  unsigned int uint4v;
typedef __attribute__((ext_vector_type(2)))  float        f32x2;
typedef __attribute__((ext_vector_type(4)))  float        f32x4;

__device__ __forceinline__ f32x2 mk2(float a, float b) { f32x2 r; r.x = a; r.y = b; return r; }

__device__ __forceinline__ float silu_f(float x) {
    float e = __expf(-x);
    return x * __builtin_amdgcn_rcpf(1.0f + e);
}
// Polynomial silu (div/exp-free): sigma(x) ~= 0.5 + t*(c0+c1*u+c2*u^2+c3*u^3),
// t = clamp(x,+-3), u = t*t. Abs err <= ~7e-4 on [-3,3] (x bounded ~+-1.5 here).
// 8 packed VALU ops per 2 elems vs 4 trans + 4 VALU for exp+rcp.
__device__ __forceinline__ f32x2 silu2(f32x2 x) {
    f32x2 t = __builtin_elementwise_min(
                  __builtin_elementwise_max(x, mk2(-3.0f, -3.0f)), mk2(3.0f, 3.0f));
    f32x2 u = t * t;
    f32x2 p = u * (-5.3638e-5f) + 1.48371e-3f;
    p = u * p + (-0.0200052f);
    p = u * p + 0.2498275f;
    f32x2 sg = t * p + 0.5f;
    return x * sg;
}
__device__ __forceinline__ unsigned short bf16_rn(float x) {
    unsigned u = __float_as_uint(x);
    u += 0x7FFF + ((u >> 16) & 1);
    return (unsigned short)(u >> 16);
}
__device__ __forceinline__ float bf16_up(unsigned short h) {
    return __uint_as_float(((unsigned)h) << 16);
}
__device__ __forceinline__ f32x2 ub2(unsigned bw) {
    return mk2(__uint_as_float(bw << 16), __uint_as_float(bw & 0xFFFF0000u));
}
__device__ __forceinline__ unsigned hpack(f32x2 a2, f32x2 w2, f32x2 b2, f32x2 d2) {
    f32x2 x2 = a2 + b2;
    x2 = __builtin_elementwise_fma(d2, w2, x2);
    f32x2 h2 = silu2(x2);
    return __builtin_amdgcn_perm(__float_as_uint(h2.y), __float_as_uint(h2.x), 0x07060302u);
}
__device__ __forceinline__ int fwd_map(int nf, int alongL) {
    if (alongL) {
        int b = nf / (LL * NN);
        int rem = nf % (LL * NN);
        int l = rem / NN, n = rem % NN;
        return (b * NN + n) * LL + l;
    }
    return nf;
}
__device__ __forceinline__ int inv_map(int gnode, int alongL) {
    if (alongL) {
        int g = gnode / LL, l = gnode % LL;
        int b = g / NN, n = g % NN;
        return (b * LL + l) * NN + n;
    }
    return gnode;
}

// ---------------------------------------------------------------------------
__global__ void k_embed(const int* __restrict__ tokens,
                        const float* __restrict__ tok_emb,
                        const float* __restrict__ pos_emb,
                        float* __restrict__ feats) {
    int idx = blockIdx.x * blockDim.x + threadIdx.x;
    if (idx < NNODE * DIM) {
        int node = idx / DIM, d = idx % DIM;
        int b = node / (LL * NN);
        int rem = node % (LL * NN);
        int n = rem % NN;
        int l = rem / NN;
        int t = tokens[b * LL + l];
        float f = tok_emb[t * DIM + d];
        if (t != PAD) f += pos_emb[(n + 2) * DIM + d];
        feats[idx] = f;
    }
}

// ---------------------------------------------------------------------------
__global__ void k_prep(const float* __restrict__ ew1, const float* __restrict__ ew2,
                       const float* __restrict__ cw1, const float* __restrict__ cb1,
                       const float* __restrict__ cw2,
                       const float* __restrict__ nw1, const float* __restrict__ nw2,
                       float* __restrict__ wdF, unsigned short* __restrict__ ew2P,
                       unsigned short* __restrict__ cw1P,
                       float* __restrict__ cbwP,
                       unsigned short* __restrict__ ew1P,
                       unsigned short* __restrict__ nw1P,
                       unsigned short* __restrict__ nw2P) {
    int idx = blockIdx.x * blockDim.x + threadIdx.x;
    if (idx < NLAY * KP) {
        int L = idx / KP, k = idx % KP;
        float v = (k < EH) ? ew1[(size_t)L * EIN * EH + 128 * EH + k] : 0.0f;
        wdF[idx] = bf16_up(bf16_rn(v));
    }
    if (idx < NLAY * NK0 * 512) {
        int L = idx / (NK0 * 512); int r = idx % (NK0 * 512);
        int k0 = r / 512; int r2 = r % 512;
        int lane = r2 >> 3, j = r2 & 7;
        int k = k0 * 16 + (lane >> 5) * 8 + j;
        int n = lane & 31;
        float v = (k < EH) ? ew2[((size_t)L * EH + k) * MDIM + n] : 0.0f;
        ew2P[idx] = bf16_rn(v);
    }
    if (idx < NLAY * 4096) {
        int L = idx / 4096; int r = idx % 4096;
        int mb = r / 1024; int r2 = r % 1024;
        int k0 = r2 / 512; int r3 = r2 % 512;
        int lane = r3 >> 3, j = r3 & 7;
        int k = k0 * 16 + (lane >> 5) * 8 + j;
        int o = mb * 32 + (lane & 31);
        cw1P[idx] = bf16_rn(cw1[((size_t)L * MDIM + k) * NH + o]);
    }
    if (idx < NLAY * 128) {
        int L = idx / 128; int r = idx % 128;
        int hlf = r / 64; int r2 = r % 64;
        int mb = r2 / 16, reg = r2 % 16;
        int o = mb * 32 + (reg & 3) + 8 * (reg >> 2) + 4 * hlf;
        cbwP[(size_t)L * 256 + r * 2 + 0] = cb1[L * NH + o];
        cbwP[(size_t)L * 256 + r * 2 + 1] = cw2[L * NH + o];
    }
    // ew1P: NT2=18 tiles; tiles 0-8 = a (c 0..287, real <258), 9-17 = b
    if (idx < NLAY * NT2 * 4 * 512) {
        int L = idx / (NT2 * 4 * 512); int r = idx % (NT2 * 4 * 512);
        int nt = r / 2048; int r2 = r % 2048;
        int ks = r2 / 512; int r3 = r2 % 512;
        int lane = r3 >> 3, j = r3 & 7;
        int d = ks * 16 + (lane >> 5) * 8 + j;
        int c = nt * 32 + (lane & 31);              // 0..575
        float v = 0.0f;
        if (c < 288) { if (c < EH) v = ew1[(size_t)L * EIN * EH + d * EH + c]; }
        else { int ob = c - 288; if (ob < EH) v = ew1[(size_t)L * EIN * EH + (DIM + d) * EH + ob]; }
        ew1P[idx] = bf16_rn(v);
    }
    if (idx < NLAY * 4 * 6 * 512) {
        int L = idx / 12288; int r = idx % 12288;
        int nt = r / 3072; int r2 = r % 3072;
        int ks = r2 / 512; int r3 = r2 % 512;
        int lane = r3 >> 3, j = r3 & 7;
        int k = ks * 16 + (lane >> 5) * 8 + j;
        int n = nt * 32 + (lane & 31);
        nw1P[idx] = bf16_rn(nw1[((size_t)L * (DIM + MDIM) + k) * NH + n]);
    }
    if (idx < NLAY * 2 * 8 * 512) {
        int L = idx / 8192; int r = idx % 8192;
        int nt = r / 4096; int r2 = r % 4096;
        int ks = r2 / 512; int r3 = r2 % 512;
        int lane = r3 >> 3, j = r3 & 7;
        int k = ks * 16 + (lane >> 5) * 8 + j;
        int n = nt * 32 + (lane & 31);
        nw2P[idx] = bf16_rn(nw2[((size_t)L * NH + k) * DIM + n]);
    }
}

// ---------------------------------------------------------------------------
// Fused node-MLP(L) + pre(L+1), 4-way N-split: grid = (NNODE/32)*4.
// ---------------------------------------------------------------------------
__global__ __launch_bounds__(256)
void k_np(const float* __restrict__ fIn, const float* __restrict__ coSrc,
          const float* __restrict__ miL, const float* __restrict__ dL,
          const unsigned short* __restrict__ nw1PL, const float* __restrict__ nb1L,
          const unsigned short* __restrict__ nw2PL, const float* __restrict__ nb2L,
          const unsigned short* __restrict__ ew1PL, const float* __restrict__ eb1L,
          float* __restrict__ fOut, float* __restrict__ coDst,
          float* __restrict__ miNext, float* __restrict__ dNext,
          unsigned short* __restrict__ aH, unsigned short* __restrict__ bH,
          int aL0, int aL1, int doNode) {
    __shared__ unsigned short xS[32 * XP];
    __shared__ unsigned short hS[32 * HP];
    __shared__ unsigned short outS[32 * OPS];
    __shared__ int gsrcS[32], gdstS[32];

    int bid  = blockIdx.x;
    int tileB = bid >> 2, par = bid & 3;
    int n0  = tileB * 32;
    int tid = threadIdx.x;
    int wave = tid >> 6, lane = tid & 63, half = lane >> 5, e = lane & 31;

    if (tid < 32) {
        gsrcS[tid] = fwd_map(n0 + tid, aL0);
        gdstS[tid] = fwd_map(n0 + tid, aL1);
    }
    __syncthreads();

    for (int i = 0; i < 8; i++) {
        int x = tid + 256 * i;
        int node = x >> 6, d = x & 63;
        xS[node * XP + d] = bf16_rn(fIn[(n0 + node) * DIM + d]);
    }
    if (doNode) {
        for (int i = 0; i < 4; i++) {
            int x = tid + 256 * i;
            int node = x >> 5, d = x & 31;
            xS[node * XP + DIM + d] = bf16_rn(miL[(size_t)gsrcS[node] * MDIM + d]);
        }
    }
    if (par == 0) {
        if (tid < 96) {
            int node = tid / 3, c = tid % 3;
            int gs = gsrcS[node], gd = gdstS[node];
            float cv = coSrc[gs * 3 + c] + (doNode ? dL[gs * 3 + c] : 0.0f);
            coDst[gd * 3 + c] = cv;
            dNext[gd * 3 + c] = 0.0f;
        }
        for (int i = 0; i < 4; i++) {
            int x = tid + 256 * i;
            int node = x >> 5, d = x & 31;
            miNext[(size_t)gdstS[node] * MDIM + d] = 0.0f;
        }
    }
    __syncthreads();

    if (doNode) {
        {
            int nt = wave;
            f32x16 acc;
#pragma unroll
            for (int q = 0; q < 16; q++) acc[q] = 0.0f;
#pragma unroll
            for (int ks = 0; ks < 6; ks++) {
                uint4v au = *(const uint4v*)(xS + e * XP + ks * 16 + half * 8);
                uint4v bu = *(const uint4v*)(nw1PL + ((size_t)(nt * 6 + ks) * 512 + lane * 8));
                acc = __builtin_amdgcn_mfma_f32_32x32x16_bf16(
                          __builtin_bit_cast(bf16x8, au),
                          __builtin_bit_cast(bf16x8, bu), acc, 0, 0, 0);
            }
            int o = nt * 32 + e;
            float b1 = nb1L[o];
#pragma unroll
            for (int q = 0; q < 16; q++) {
                int row = (q & 3) + 8 * (q >> 2) + 4 * half;
                hS[row * HP + o] = bf16_rn(silu_f(acc[q] + b1));
            }
        }
        __syncthreads();

        if (wave < 2) {
            int nt = wave;
            f32x16 acc;
#pragma unroll
            for (int q = 0; q < 16; q++) acc[q] = 0.0f;
#pragma unroll
            for (int ks = 0; ks < 8; ks++) {
                uint4v au = *(const uint4v*)(hS + e * HP + ks * 16 + half * 8);
                uint4v bu = *(const uint4v*)(nw2PL + ((size_t)(nt * 8 + ks) * 512 + lane * 8));
                acc = __builtin_amdgcn_mfma_f32_32x32x16_bf16(
                          __builtin_bit_cast(bf16x8, au),
                          __builtin_bit_cast(bf16x8, bu), acc, 0, 0, 0);
            }
            int o = nt * 32 + e;
            float b2 = nb2L[o];
#pragma unroll
            for (int q = 0; q < 16; q++) {
                int row = (q & 3) + 8 * (q >> 2) + 4 * half;
                float fo = acc[q] + b2 + bf16_up(xS[row * XP + o]);
                if (par == 0) fOut[(size_t)(n0 + row) * DIM + o] = fo;
                xS[row * XP + o] = bf16_rn(fo);
            }
        }
        __syncthreads();
    }

    // ---- GEMM3: this block's tiles nt = par + lt*4 ----
    {
        uint4v afrag[4];
#pragma unroll
        for (int ks = 0; ks < 4; ks++)
            afrag[ks] = *(const uint4v*)(xS + e * XP + ks * 16 + half * 8);

        for (int lt = wave; lt < 5; lt += 4) {
            int nt = par + lt * 4;
            if (nt >= NT2) continue;
            f32x16 acc;
#pragma unroll
            for (int q = 0; q < 16; q++) acc[q] = 0.0f;
#pragma unroll
            for (int ks = 0; ks < 4; ks++) {
                uint4v bu = *(const uint4v*)(ew1PL + ((size_t)(nt * 4 + ks) * 512 + lane * 8));
                acc = __builtin_amdgcn_mfma_f32_32x32x16_bf16(
                          __builtin_bit_cast(bf16x8, afrag[ks]),
                          __builtin_bit_cast(bf16x8, bu), acc, 0, 0, 0);
            }
            int c = nt * 32 + e;
            bool isA = c < 288;
            int oc = isA ? c : (c - 288);
            bool valid = oc < EH;
            float eb = (isA && valid) ? eb1L[oc] : 0.0f;
#pragma unroll
            for (int q = 0; q < 16; q++) {
                int row = (q & 3) + 8 * (q >> 2) + 4 * half;
                float v = valid ? (acc[q] + eb) : 0.0f;
                outS[row * OPS + lt * 32 + e] = bf16_rn(v);
            }
        }
    }
    __syncthreads();

    // ---- coalesced writeback of owned 16B chunks ----
    {
        int nch = (par < 2) ? 20 : 16;
        for (int x = tid; x < 32 * nch; x += 256) {
            int row = x / nch, cl = x % nch;
            int lt = cl >> 2, sub = cl & 3;
            int nt = par + lt * 4;
            uint4v v = *(const uint4v*)(outS + row * OPS + lt * 32 + sub * 8);
            int gd = gdstS[row];
            if (nt < 9) {
                int col = nt * 32 + sub * 8;
                if (col < KP) *(uint4v*)(aH + (size_t)gd * KP + col) = v;
            } else {
                int col = (nt - 9) * 32 + sub * 8;
                if (col < KP) *(uint4v*)(bH + (size_t)gd * KP + col) = v;
            }
        }
    }
}

// ---------------------------------------------------------------------------
// MFMA edge kernel — R6 structure + polynomial silu (trans-free hot path).
// ---------------------------------------------------------------------------
__global__ __launch_bounds__(256, 4)
void k_edge(const unsigned short* __restrict__ aH,
            const unsigned short* __restrict__ bH,
            const float* __restrict__ coorsO,
            const float* __restrict__ wdFL,
            const unsigned short* __restrict__ ew2PL,
            const float* __restrict__ eb2L,
            const unsigned short* __restrict__ cw1PL,
            const float* __restrict__ cbwPL,
            const float* __restrict__ cb2L,
            const float* __restrict__ lnbL,
            float* __restrict__ miBuf, float* __restrict__ deltaBuf,
            int Nn, int itpg, int njt) {
    __shared__ unsigned short bS[32 * BPITCH];
    __shared__ __align__(16) float aSf[8 * APITCH];
    __shared__ __align__(16) float wdS[KP];
    __shared__ float cjS[32 * 3];
    __shared__ __align__(16) float cbwS[256];
    __shared__ unsigned short mT[4][32 * 36];

    int bid = blockIdx.x;
    int g   = bid / (itpg * njt);
    int r   = bid % (itpg * njt);
    int it  = r / njt;
    int jt  = r % njt;

    int tid  = threadIdx.x;
    int wave = tid >> 6, lane = tid & 63, half = lane >> 5, e = lane & 31;

    int j0  = jt * 32;
    int njr = Nn - j0; if (njr > 32) njr = 32;
    int i0  = it * 8;
    int nir = Nn - i0; if (nir > 8) nir = 8;

    {
        const unsigned int* src = (const unsigned int*)(bH + (size_t)(g * Nn + j0) * KP);
        unsigned int* dst = (unsigned int*)bS;
        int tot = njr * 136;
        for (int x = tid; x < tot; x += 256) {
            int rr = x / 136, c = x % 136;
            dst[rr * (BPITCH / 2) + c] = src[rr * 136 + c];
        }
        const unsigned short* asrc = aH + (size_t)(g * Nn + i0) * KP;
        int at = nir * KP;
        for (int x = tid; x < at; x += 256) {
            int rr = x / KP, k = x % KP;
            aSf[rr * APITCH + k] = bf16_up(asrc[rr * KP + k]);
        }
        for (int x = tid; x < KP; x += 256) wdS[x] = wdFL[x];
        if (tid < njr * 3) cjS[tid] = coorsO[(g * Nn + j0) * 3 + tid];
        if (tid < 256) cbwS[tid] = cbwPL[tid];
    }
    __syncthreads();

    float eb2v = eb2L[e];
    float beta = lnbL[0];
    float cb2v = cb2L[0];

    int  jc     = (e < njr) ? e : (njr - 1);
    bool jvalid = (e < njr);
    float cjx = cjS[jc * 3 + 0], cjy = cjS[jc * 3 + 1], cjz = cjS[jc * 3 + 2];

    unsigned short* mW = &mT[wave][0];
    const unsigned short* bRow = bS + jc * BPITCH;

    int il0 = wave * 2, il1 = wave * 2 + 1;
    bool v0 = il0 < nir, v1 = il1 < nir;
    int gi0 = g * Nn + i0 + (v0 ? il0 : 0);
    int gi1 = g * Nn + i0 + (v1 ? il1 : 0);

    float rx0, ry0, rz0, d0, rx1, ry1, rz1, d1;
    {
        float cx = coorsO[gi0 * 3 + 0], cy = coorsO[gi0 * 3 + 1], cz = coorsO[gi0 * 3 + 2];
        rx0 = cx - cjx; ry0 = cy - cjy; rz0 = cz - cjz;
        d0 = rx0 * rx0 + ry0 * ry0 + rz0 * rz0;
        cx = coorsO[gi1 * 3 + 0]; cy = coorsO[gi1 * 3 + 1]; cz = coorsO[gi1 * 3 + 2];
        rx1 = cx - cjx; ry1 = cy - cjy; rz1 = cz - cjz;
        d1 = rx1 * rx1 + ry1 * ry1 + rz1 * rz1;
    }
    f32x2 d20 = mk2(d0, d0), d21 = mk2(d1, d1);
    const float* aR0 = aSf + (v0 ? il0 : 0) * APITCH;
    const float* aR1 = aSf + (v1 ? il1 : 0) * APITCH;

    f32x16 acc0, acc1;
#pragma unroll
    for (int q = 0; q < 16; q++) { acc0[q] = 0.0f; acc1[q] = 0.0f; }

#pragma unroll
    for (int k0 = 0; k0 < NK0; k0++) {
        int ko = k0 * 16 + half * 8;
        uint2 bA = *(const uint2*)(bRow + ko);
        uint2 bB = *(const uint2*)(bRow + ko + 4);
        f32x4 wv0 = *(const f32x4*)(wdS + ko);
        f32x4 wv1 = *(const f32x4*)(wdS + ko + 4);
        uint4v eu = *(const uint4v*)(ew2PL + ((size_t)k0 * 64 + lane) * 8);
        f32x2 b2_0 = ub2(bA.x), b2_1 = ub2(bA.y), b2_2 = ub2(bB.x), b2_3 = ub2(bB.y);

        f32x4 a00 = *(const f32x4*)(aR0 + ko);
        f32x4 a01 = *(const f32x4*)(aR0 + ko + 4);
        uint4v hu0;
        hu0[0] = hpack(a00.xy, wv0.xy, b2_0, d20);
        hu0[1] = hpack(a00.zw, wv0.zw, b2_1, d20);
        hu0[2] = hpack(a01.xy, wv1.xy, b2_2, d20);
        hu0[3] = hpack(a01.zw, wv1.zw, b2_3, d20);
        acc0 = __builtin_amdgcn_mfma_f32_32x32x16_bf16(
                   __builtin_bit_cast(bf16x8, hu0),
                   __builtin_bit_cast(bf16x8, eu), acc0, 0, 0, 0);

        f32x4 a10 = *(const f32x4*)(aR1 + ko);
        f32x4 a11 = *(const f32x4*)(aR1 + ko + 4);
        uint4v hu1;
        hu1[0] = hpack(a10.xy, wv0.xy, b2_0, d21);
        hu1[1] = hpack(a10.zw, wv0.zw, b2_1, d21);
        hu1[2] = hpack(a11.xy, wv1.xy, b2_2, d21);
        hu1[3] = hpack(a11.zw, wv1.zw, b2_3, d21);
        acc1 = __builtin_amdgcn_mfma_f32_32x32x16_bf16(
                   __builtin_bit_cast(bf16x8, hu1),
                   __builtin_bit_cast(bf16x8, eu), acc1, 0, 0, 0);
    }

    f32x2 ebp = mk2(eb2v, eb2v);

#pragma unroll
    for (int s = 0; s < 2; s++) {
        if (!(s ? v1 : v0)) continue;
        int gi = s ? gi1 : gi0;
        float rx = s ? rx1 : rx0, ry = s ? ry1 : ry0, rz = s ? rz1 : rz0;
        float dist = s ? d1 : d0;

        float mv[16];
        f32x2 mi2 = mk2(0.0f, 0.0f);
        if (njr == 32) {
#pragma unroll
            for (int qp = 0; qp < 8; qp++) {
                int q = qp * 2;
                f32x2 x2 = mk2(s ? acc1[q] : acc0[q], s ? acc1[q + 1] : acc0[q + 1]) + ebp;
                f32x2 m2 = silu2(x2);
                mv[q] = m2.x; mv[q + 1] = m2.y;
                mi2 += m2;
            }
        } else {
#pragma unroll
            for (int qp = 0; qp < 8; qp++) {
                int q = qp * 2;
                f32x2 x2 = mk2(s ? acc1[q] : acc0[q], s ? acc1[q + 1] : acc0[q + 1]) + ebp;
                f32x2 m2 = silu2(x2);
                int row0 = (q & 3) + 8 * (q >> 2) + 4 * half;
                if (j0 + row0 >= Nn) m2.x = 0.0f;
                if (j0 + row0 + 1 >= Nn) m2.y = 0.0f;
                mv[q] = m2.x; mv[q + 1] = m2.y;
                mi2 += m2;
            }
        }
        float miAcc = mi2.x + mi2.y;

#pragma unroll
        for (int q = 0; q < 4; q++) {
            unsigned lo = __builtin_amdgcn_perm(__float_as_uint(mv[q * 4 + 1]),
                                                __float_as_uint(mv[q * 4 + 0]), 0x07060302u);
            unsigned hi = __builtin_amdgcn_perm(__float_as_uint(mv[q * 4 + 3]),
                                                __float_as_uint(mv[q * 4 + 2]), 0x07060302u);
            int row0 = 8 * q + 4 * half;
            *(uint2*)&mW[e * 36 + row0] = make_uint2(lo, hi);
        }

        miAcc += __shfl_xor(miAcc, 32, 64);
        if (half == 0) atomicAdd(&miBuf[gi * MDIM + e], miAcc);

        bf16x8 bq[2];
#pragma unroll
        for (int k0 = 0; k0 < 2; k0++) {
            uint4v t;
#pragma unroll
            for (int p = 0; p < 4; p++) {
                unsigned w0 = mW[(k0 * 16 + half * 8 + 2 * p    ) * 36 + e];
                unsigned w1 = mW[(k0 * 16 + half * 8 + 2 * p + 1) * 36 + e];
                t[p] = w0 | (w1 << 16);
            }
            bq[k0] = __builtin_bit_cast(bf16x8, t);
        }

        f32x2 w2a = mk2(0.0f, 0.0f);
#pragma unroll
        for (int mb = 0; mb < 4; mb++) {
            f32x16 sacc;
#pragma unroll
            for (int q = 0; q < 16; q++) sacc[q] = 0.0f;
#pragma unroll
            for (int k0 = 0; k0 < 2; k0++) {
                uint4v cu = *(const uint4v*)(cw1PL + ((size_t)(mb * 2 + k0) * 64 + lane) * 8);
                sacc = __builtin_amdgcn_mfma_f32_32x32x16_bf16(
                           __builtin_bit_cast(bf16x8, cu), bq[k0], sacc, 0, 0, 0);
            }
            const f32x4* cv = (const f32x4*)(cbwS + (half * 4 + mb) * 32);
#pragma unroll
            for (int qp = 0; qp < 8; qp++) {
                f32x4 c4 = cv[qp];
                f32x2 s2 = mk2(sacc[2 * qp], sacc[2 * qp + 1]) + mk2(c4.x, c4.z);
                f32x2 p2 = silu2(s2);
                w2a = __builtin_elementwise_fma(p2, mk2(c4.y, c4.w), w2a);
            }
        }
        float wAcc = w2a.x + w2a.y;
        wAcc += __shfl_xor(wAcc, 32, 64);
        float w = wAcc + cb2v;
        float nrm = sqrtf(dist);
        float scale = (w * 0.02f) * beta * __builtin_amdgcn_rcpf(fmaxf(nrm, 1e-8f));

        float dAx = 0.0f, dAy = 0.0f, dAz = 0.0f;
        if (jvalid && half == 0) {
            dAx = scale * rx; dAy = scale * ry; dAz = scale * rz;
        }
#pragma unroll
        for (int m = 16; m >= 1; m >>= 1) {
            dAx += __shfl_xor(dAx, m, 64);
            dAy += __shfl_xor(dAy, m, 64);
            dAz += __shfl_xor(dAz, m, 64);
        }
        if (lane == 0) {
            atomicAdd(&deltaBuf[gi * 3 + 0], dAx);
            atomicAdd(&deltaBuf[gi * 3 + 1], dAy);
            atomicAdd(&deltaBuf[gi * 3 + 2], dAz);
        }
    }
}

// ---------------------------------------------------------------------------
__global__ void k_fin(const float* __restrict__ co, const float* __restrict__ dl,
                      float* __restrict__ out) {
    int idx = blockIdx.x * blockDim.x + threadIdx.x;
    if (idx < NNODE * 3) {
        int gnode = idx / 3, c = idx % 3;
        int nf = inv_map(gnode, 1);   // layer 15 is along-l
        out[nf * 3 + c] = co[idx] + dl[idx];
    }
}

// ---------------------------------------------------------------------------
extern "C" void kernel_launch(void* const* d_in, const int* in_sizes, int n_in,
                              void* d_out, int out_size, void* d_ws, size_t ws_size,
                              hipStream_t stream) {
    (void)in_sizes; (void)n_in; (void)out_size; (void)ws_size;

    const int*   tokens  = (const int*)d_in[0];
    const float* cords   = (const float*)d_in[1];
    const float* tok_emb = (const float*)d_in[2];
    const float* pos_emb = (const float*)d_in[3];
    const float* ew1 = (const float*)d_in[4];
    const float* eb1 = (const float*)d_in[5];
    const float* ew2 = (const float*)d_in[6];
    const float* eb2 = (const float*)d_in[7];
    const float* cw1 = (const float*)d_in[8];
    const float* cb1 = (const float*)d_in[9];
    const float* cw2 = (const float*)d_in[10];
    const float* cb2 = (const float*)d_in[11];
    const float* nw1 = (const float*)d_in[12];
    const float* nb1 = (const float*)d_in[13];
    const float* nw2 = (const float*)d_in[14];
    const float* nb2 = (const float*)d_in[15];
    /* d_in[16] = ln_g : multiplied by zeros in the reference -> unused */
    const float* lnb = (const float*)d_in[17];

    float* wf = (float*)d_ws;
    float* featsA = wf; wf += NNODE * DIM;
    float* featsB = wf; wf += NNODE * DIM;
    float* coorsO0 = wf; wf += NNODE * 3;
    float* coorsO1 = wf; wf += NNODE * 3;
    float* mi0  = wf; wf += NNODE * MDIM;
    float* mi1  = wf; wf += NNODE * MDIM;
    float* dl0  = wf; wf += NNODE * 3;
    float* dl1  = wf; wf += NNODE * 3;
    float* cbwP = wf; wf += NLAY * 256;
    float* wdF  = wf; wf += NLAY * KP;

    uintptr_t p = (uintptr_t)wf; p = (p + 15) & ~(uintptr_t)15;
    unsigned short* wh = (unsigned short*)p;
    unsigned short* aHb  = wh; wh += (size_t)NNODE * KP;
    unsigned short* bHb  = wh; wh += (size_t)NNODE * KP;
    unsigned short* ew2P = wh; wh += NLAY * NK0 * 512;
    unsigned short* cw1P = wh; wh += NLAY * 4096;
    unsigned short* ew1P = wh; wh += (size_t)NLAY * NT2 * 4 * 512;
    unsigned short* nw1P = wh; wh += (size_t)NLAY * 4 * 6 * 512;
    unsigned short* nw2P = wh; wh += (size_t)NLAY * 2 * 8 * 512;

    float* coorsO[2] = {coorsO0, coorsO1};
    float* miB[2]    = {mi0, mi1};
    float* dlB[2]    = {dl0, dl1};

    int prepN = NLAY * NT2 * 4 * 512;
    k_prep<<<(prepN + 255) / 256, 256, 0, stream>>>(
        ew1, ew2, cw1, cb1, cw2, nw1, nw2,
        wdF, ew2P, cw1P, cbwP, ew1P, nw1P, nw2P);
    k_embed<<<(NNODE * DIM + 255) / 256, 256, 0, stream>>>(
        tokens, tok_emb, pos_emb, featsA);

    float* fCur = featsA; float* fNxt = featsB;

    k_np<<<(NNODE / 32) * 4, 256, 0, stream>>>(
        fCur, cords, nullptr, nullptr,
        nullptr, nullptr, nullptr, nullptr,
        ew1P + 0, eb1 + 0,
        fNxt, coorsO[0], miB[0], dlB[0],
        aHb, bHb, 0, 0, 0);

    for (int L = 0; L < NLAY; L++) {
        int alongL = (L / 4) % 2;
        int idx  = L & 1;
        int Nn   = alongL ? LL : NN;
        int njt  = alongL ? 3 : 1;
        int itpg = (Nn + 7) / 8;
        int groups = NNODE / Nn;

        k_edge<<<groups * itpg * njt, 256, 0, stream>>>(
            aHb, bHb, coorsO[idx],
            wdF + L * KP, ew2P + (size_t)L * NK0 * 512, eb2 + L * MDIM,
            cw1P + (size_t)L * 4096, cbwP + (size_t)L * 256,
            cb2 + L, lnb + L, miB[idx], dlB[idx], Nn, itpg, njt);

        if (L < NLAY - 1) {
            int aL1 = ((L + 1) / 4) % 2;
            int nidx = (L + 1) & 1;
            k_np<<<(NNODE / 32) * 4, 256, 0, stream>>>(
                fCur, coorsO[idx], miB[idx], dlB[idx],
                nw1P + (size_t)L * 4 * 6 * 512, nb1 + L * NH,
                nw2P + (size_t)L * 2 * 8 * 512, nb2 + L * DIM,
                ew1P + (size_t)(L + 1) * NT2 * 4 * 512, eb1 + (size_t)(L + 1) * EH,
                fNxt, coorsO[nidx], miB[nidx], dlB[nidx],
                aHb, bHb, alongL, aL1, 1);
            float* t = fCur; fCur = fNxt; fNxt = t;
        } else {
            k_fin<<<(NNODE * 3 + 255) / 256, 256, 0, stream>>>(
                coorsO[idx], dlB[idx], (float*)d_out);
        }
    }
}